// Round 1
// 510.249 us; speedup vs baseline: 1.0156x; 1.0156x over previous
//
#include <hip/hip_runtime.h>

#define N_NODES 50000
#define F_IN 500
#define F_HID 128
#define F_OUT 16
#define NSCAN_BLKS ((N_NODES + 255) / 256)   // 196

// ---------------- bf16 helpers (RTNE pack, shift decode) ----------------

__device__ __forceinline__ unsigned bf16_pack2(float a, float b) {
    unsigned ua = __float_as_uint(a);
    unsigned ub = __float_as_uint(b);
    ua = (ua + 0x7fffu + ((ua >> 16) & 1u)) >> 16;
    ub = (ub + 0x7fffu + ((ub >> 16) & 1u)) >> 16;
    return ua | (ub << 16);
}
__device__ __forceinline__ float bf_lo(unsigned v) { return __uint_as_float(v << 16); }
__device__ __forceinline__ float bf_hi(unsigned v) { return __uint_as_float(v & 0xffff0000u); }

__device__ __forceinline__ unsigned bf16_rtne(float a) {
    unsigned u = __float_as_uint(a);
    return (u + 0x7fffu + ((u >> 16) & 1u)) >> 16;
}

// ---------------- CSR build (single atomic pass, round-9 proven) ----------------

__global__ void k_hist_rank(const int* __restrict__ dst, int* __restrict__ hist,
                            int* __restrict__ rank, int E) {
    int e = blockIdx.x * 256 + threadIdx.x;
    if (e < E) rank[e] = atomicAdd(&hist[dst[e]], 1);
}

__global__ __launch_bounds__(256) void k_scan_local(const int* __restrict__ hist,
                                                    int* __restrict__ rowptr,
                                                    int* __restrict__ blksum) {
    __shared__ int s[256];
    const int tid = threadIdx.x;
    const int i = blockIdx.x * 256 + tid;
    int v = (i < N_NODES) ? hist[i] : 0;
    s[tid] = v;
    __syncthreads();
#pragma unroll
    for (int ofs = 1; ofs < 256; ofs <<= 1) {
        int t = (tid >= ofs) ? s[tid - ofs] : 0;
        __syncthreads();
        if (tid >= ofs) s[tid] += t;
        __syncthreads();
    }
    if (i < N_NODES) rowptr[i] = s[tid] - v;
    if (tid == 255) blksum[blockIdx.x] = s[255];
}

__global__ __launch_bounds__(256) void k_scan_blk(int* __restrict__ blksum) {
    __shared__ int s[256];
    const int tid = threadIdx.x;
    int v = (tid < NSCAN_BLKS) ? blksum[tid] : 0;
    s[tid] = v;
    __syncthreads();
#pragma unroll
    for (int ofs = 1; ofs < 256; ofs <<= 1) {
        int t = (tid >= ofs) ? s[tid - ofs] : 0;
        __syncthreads();
        if (tid >= ofs) s[tid] += t;
        __syncthreads();
    }
    if (tid < NSCAN_BLKS) blksum[tid] = s[tid] - v;
}

__global__ void k_finalize(const int* __restrict__ hist, int* __restrict__ rowptr,
                           const int* __restrict__ blksum, float* __restrict__ isd, int E) {
    int i = blockIdx.x * 256 + threadIdx.x;
    if (i < N_NODES) {
        rowptr[i] = rowptr[i] + blksum[i >> 8];
        isd[i] = rsqrtf((float)(hist[i] + 1));  // +1 self-loop
    }
    if (i == 0) rowptr[N_NODES] = E;
}

__global__ void k_reorder(const int* __restrict__ src, const int* __restrict__ dst,
                          const int* __restrict__ rank, const int* __restrict__ rowptr,
                          int* __restrict__ csr_src, int E) {
    int e = blockIdx.x * 256 + threadIdx.x;
    if (e >= E) return;
    csr_src[rowptr[dst[e]] + rank[e]] = src[e];
}

// ---------------- Wc = Wlin @ W2  [16,128] ----------------

__global__ void k_wc(const float* __restrict__ W2, const float* __restrict__ Wlin,
                     float* __restrict__ Wc) {
    const int c = blockIdx.x;       // 0..15
    const int j = threadIdx.x;      // 0..127
    const float* wl = Wlin + c * 128;
    float acc = 0.f;
#pragma unroll 4
    for (int k = 0; k < 128; ++k) acc += wl[k] * W2[k * 128 + j];
    Wc[c * 128 + j] = acc;
}

// ---------------- W1 split: fp32 -> bf16 hi + bf16 residual, padded K 500->512 ----------------

__global__ __launch_bounds__(256) void k_w1split(const float* __restrict__ W1,
                                                 ushort* __restrict__ w1hi,
                                                 ushort* __restrict__ w1lo) {
    int idx = blockIdx.x * 256 + threadIdx.x;   // 128*512
    if (idx >= 128 * 512) return;
    int n = idx >> 9, k = idx & 511;
    float v = (k < F_IN) ? W1[n * F_IN + k] : 0.f;
    unsigned h = bf16_rtne(v);
    float fh = __uint_as_float(h << 16);
    unsigned l = bf16_rtne(v - fh);              // Dekker split: v - bf16(v) exact in fp32
    w1hi[idx] = (ushort)h;
    w1lo[idx] = (ushort)l;
}

// ---------------- GEMM1 via MFMA: hb[M,128](bf16) = A[M,K] @ W1^T ----------------
// 3-pass split (Ahi*Whi + Alo*Whi + Ahi*Wlo) keeps fp32-equivalent accuracy
// before the bf16 store (residual O(2^-18) per product).
// Layout (guide §3, m89-verified, 16x16x32 bf16):
//   A-frag: row = lane&15, k = (lane>>4)*8 + j  -> 8 consecutive fp32 per lane
//   B-frag: col = lane&15 (= W1 row), same k slice
//   D:      col = lane&15, row = (lane>>4)*4 + r

typedef __attribute__((ext_vector_type(8))) short s16x8;
typedef __attribute__((ext_vector_type(4))) float f32x4;

__global__ __launch_bounds__(256) void gemm1_mfma(const float* __restrict__ A,
                                                  const ushort* __restrict__ w1hi,
                                                  const ushort* __restrict__ w1lo,
                                                  unsigned* __restrict__ hb, int M) {
    const int lane = threadIdx.x & 63;
    const int wave = threadIdx.x >> 6;        // 0..3
    const int jcol = lane & 15;               // A-frag row within strip / D col within frag
    const int kgrp = lane >> 4;               // 0..3
    const int klo  = kgrp << 3;               // 0,8,16,24

    const int m0  = blockIdx.x * 64 + wave * 16;   // wave's 16-row strip
    const int arw = m0 + jcol;
    const float* arow = A + (size_t)((arw < M) ? arw : (M - 1)) * F_IN;

    f32x4 acc[8] = {};

    const size_t bbase = ((size_t)jcol << 9);      // jcol*512

    for (int kt = 0; kt < 16; ++kt) {
        const int k = (kt << 5) + klo;
        // ---- load 8 fp32 of A (guarded at the K=500 tail) ----
        float av[8];
        if (k + 8 <= F_IN) {
            float4 p0 = *(const float4*)(arow + k);
            float4 p1 = *(const float4*)(arow + k + 4);
            av[0] = p0.x; av[1] = p0.y; av[2] = p0.z; av[3] = p0.w;
            av[4] = p1.x; av[5] = p1.y; av[6] = p1.z; av[7] = p1.w;
        } else {
#pragma unroll
            for (int i = 0; i < 8; ++i) av[i] = (k + i < F_IN) ? arow[k + i] : 0.f;
        }
        // ---- Dekker split to bf16 hi/lo fragments ----
        s16x8 ahi, alo;
#pragma unroll
        for (int i = 0; i < 8; ++i) {
            unsigned h = bf16_rtne(av[i]);
            float fh = __uint_as_float(h << 16);
            unsigned l = bf16_rtne(av[i] - fh);
            ahi[i] = (short)h;
            alo[i] = (short)l;
        }
        // ---- 8 column fragments x 3 MFMA passes ----
#pragma unroll
        for (int f = 0; f < 8; ++f) {
            const s16x8 bhi = *(const s16x8*)(w1hi + bbase + ((size_t)f << 13) + k);
            const s16x8 blo = *(const s16x8*)(w1lo + bbase + ((size_t)f << 13) + k);
            acc[f] = __builtin_amdgcn_mfma_f32_16x16x32_bf16(ahi, bhi, acc[f], 0, 0, 0);
            acc[f] = __builtin_amdgcn_mfma_f32_16x16x32_bf16(alo, bhi, acc[f], 0, 0, 0);
            acc[f] = __builtin_amdgcn_mfma_f32_16x16x32_bf16(ahi, blo, acc[f], 0, 0, 0);
        }
    }

    // ---- epilogue: pack adjacent features via shfl, write uint u = (feat 2u, 2u+1) ----
    const int orow = m0 + (kgrp << 2);
#pragma unroll
    for (int f = 0; f < 8; ++f) {
#pragma unroll
        for (int r = 0; r < 4; ++r) {
            float v = acc[f][r];
            float o = __shfl_xor(v, 1, 64);
            if (!(jcol & 1)) {
                const int m = orow + r;
                if (m < M)
                    hb[(size_t)m * 64 + (f << 3) + (jcol >> 1)] = bf16_pack2(v, o);
            }
        }
    }
}

// ---------------- fused gather + zlin, TWO waves per node (round-9 proven) ----------------

__device__ __forceinline__ void gather_range(const unsigned* __restrict__ hh,
                                             const int* __restrict__ csr_src,
                                             const float* __restrict__ isd,
                                             float si, int lane, int e, int end,
                                             float& accx, float& accy) {
    int s[8], t[8];
    bool have = (e + 8 <= end);
    if (have) {
#pragma unroll
        for (int i = 0; i < 8; ++i) s[i] = csr_src[e + i];
    }
    while (have) {
        unsigned v[8];
        float w[8];
#pragma unroll
        for (int i = 0; i < 8; ++i) v[i] = hh[(size_t)s[i] * 64 + lane];
#pragma unroll
        for (int i = 0; i < 8; ++i) w[i] = isd[s[i]];
        const int ne = e + 8;
        const bool nhave = (ne + 8 <= end);
        if (nhave) {
#pragma unroll
            for (int i = 0; i < 8; ++i) t[i] = csr_src[ne + i];
        }
#pragma unroll
        for (int i = 0; i < 8; ++i) {
            const float wi = w[i] * si;
            accx += wi * bf_lo(v[i]);
            accy += wi * bf_hi(v[i]);
        }
#pragma unroll
        for (int i = 0; i < 8; ++i) s[i] = t[i];
        e = ne;
        have = nhave;
    }
    for (; e < end; ++e) {
        const int ss = csr_src[e];
        const float wi = isd[ss] * si;
        const unsigned v = hh[(size_t)ss * 64 + lane];
        accx += wi * bf_lo(v);
        accy += wi * bf_hi(v);
    }
}

__global__ __launch_bounds__(256) void k_gather_fused2(const unsigned* __restrict__ hh,
                                                       const int* __restrict__ rowptr,
                                                       const int* __restrict__ csr_src,
                                                       const float* __restrict__ isd,
                                                       const float* __restrict__ Wc,
                                                       float* __restrict__ z) {
    __shared__ float2 part[2][64];
    const int tid = threadIdx.x;
    const int lane = tid & 63;
    const int waveid = tid >> 6;         // 0..3
    const int slot = waveid >> 1;        // node slot 0..1
    const int half = waveid & 1;         // 0 = primary, 1 = secondary
    const int node = (blockIdx.x << 1) + slot;   // < 50000 always (grid=25000)

    const float si = isd[node];
    const int e0 = rowptr[node], e1 = rowptr[node + 1];
    const int mid = e0 + ((e1 - e0) >> 1);

    float accx = 0.f, accy = 0.f;
    if (half == 0) {
        const unsigned a = hh[(size_t)node * 64 + lane];   // self-loop
        accx = bf_lo(a) * si * si;
        accy = bf_hi(a) * si * si;
        gather_range(hh, csr_src, isd, si, lane, e0, mid, accx, accy);
    } else {
        gather_range(hh, csr_src, isd, si, lane, mid, e1, accx, accy);
        part[slot][lane] = make_float2(accx, accy);
    }
    __syncthreads();
    if (half == 1) return;

    const float2 pb = part[slot][lane];
    accx += pb.x;
    accy += pb.y;

    // relu + Wc dot + wave reduction
    const float rx = fmaxf(accx, 0.f), ry = fmaxf(accy, 0.f);
    float p[16];
#pragma unroll
    for (int c = 0; c < 16; ++c) {
        const float2 wc = *(const float2*)(Wc + c * 128 + (lane << 1));
        p[c] = rx * wc.x + ry * wc.y;
    }
#pragma unroll
    for (int m = 1; m < 64; m <<= 1) {
#pragma unroll
        for (int c = 0; c < 16; ++c) p[c] += __shfl_xor(p[c], m, 64);
    }
    if (lane == 0) {
        float* zr = z + (size_t)node * 16;
        *(float4*)(zr + 0)  = make_float4(p[0],  p[1],  p[2],  p[3]);
        *(float4*)(zr + 4)  = make_float4(p[4],  p[5],  p[6],  p[7]);
        *(float4*)(zr + 8)  = make_float4(p[8],  p[9],  p[10], p[11]);
        *(float4*)(zr + 12) = make_float4(p[12], p[13], p[14], p[15]);
    }
}

// ---------------- gather (16-wide): 4 threads per node ----------------

__global__ __launch_bounds__(256) void k_gather16(const float4* __restrict__ z4,
                                                  const int* __restrict__ rowptr,
                                                  const int* __restrict__ csr_src,
                                                  const float* __restrict__ isd,
                                                  float4* __restrict__ out4) {
    int t = blockIdx.x * 256 + threadIdx.x;
    int n = t >> 2, q = t & 3;
    if (n >= N_NODES) return;
    const float si = isd[n];
    float4 a = z4[(size_t)n * 4 + q];
    float4 acc;
    acc.x = a.x * si * si; acc.y = a.y * si * si;
    acc.z = a.z * si * si; acc.w = a.w * si * si;
    int e = rowptr[n];
    const int end = rowptr[n + 1];
    for (; e + 4 <= end; e += 4) {
        int s0 = csr_src[e],     s1 = csr_src[e + 1];
        int s2 = csr_src[e + 2], s3 = csr_src[e + 3];
        float w0 = isd[s0] * si, w1 = isd[s1] * si;
        float w2 = isd[s2] * si, w3 = isd[s3] * si;
        float4 v0 = z4[(size_t)s0 * 4 + q];
        float4 v1 = z4[(size_t)s1 * 4 + q];
        float4 v2 = z4[(size_t)s2 * 4 + q];
        float4 v3 = z4[(size_t)s3 * 4 + q];
        acc.x += w0 * v0.x; acc.y += w0 * v0.y; acc.z += w0 * v0.z; acc.w += w0 * v0.w;
        acc.x += w1 * v1.x; acc.y += w1 * v1.y; acc.z += w1 * v1.z; acc.w += w1 * v1.w;
        acc.x += w2 * v2.x; acc.y += w2 * v2.y; acc.z += w2 * v2.z; acc.w += w2 * v2.w;
        acc.x += w3 * v3.x; acc.y += w3 * v3.y; acc.z += w3 * v3.z; acc.w += w3 * v3.w;
    }
    for (; e < end; ++e) {
        int s = csr_src[e];
        float w = isd[s] * si;
        float4 v = z4[(size_t)s * 4 + q];
        acc.x += w * v.x; acc.y += w * v.y; acc.z += w * v.z; acc.w += w * v.w;
    }
    out4[(size_t)n * 4 + q] = acc;
}

// ---------------- fallback (round-1 atomic path, all fp32) ----------------

__global__ void k_deg_init(float* __restrict__ deg) {
    int i = blockIdx.x * 256 + threadIdx.x;
    if (i < N_NODES) deg[i] = 1.0f;
}
__global__ void k_deg_count(const int* __restrict__ dst, float* __restrict__ deg, int E) {
    int e = blockIdx.x * 256 + threadIdx.x;
    if (e < E) atomicAdd(&deg[dst[e]], 1.0f);
}
__global__ void k_rsqrt(float* __restrict__ deg) {
    int i = blockIdx.x * 256 + threadIdx.x;
    if (i < N_NODES) deg[i] = rsqrtf(deg[i]);
}
__global__ void k_agg_init(const float4* __restrict__ h, const float* __restrict__ isd,
                           float4* __restrict__ agg) {
    int t = blockIdx.x * 256 + threadIdx.x;
    if (t < N_NODES * (F_HID / 4)) {
        int row = t >> 5;
        float s = isd[row];
        s = s * s;
        float4 v = h[t];
        v.x *= s; v.y *= s; v.z *= s; v.w *= s;
        agg[t] = v;
    }
}
__global__ void k_scatter(const float4* __restrict__ h, const int* __restrict__ src,
                          const int* __restrict__ dst, const float* __restrict__ isd,
                          float* __restrict__ agg, int E) {
    int t = blockIdx.x * 256 + threadIdx.x;
    int e = t >> 5, q = t & 31;
    if (e >= E) return;
    int s = src[e], d = dst[e];
    float norm = isd[s] * isd[d];
    float4 v = h[(long long)s * 32 + q];
    float* out = agg + (long long)d * F_HID + q * 4;
    atomicAdd(out + 0, v.x * norm);
    atomicAdd(out + 1, v.y * norm);
    atomicAdd(out + 2, v.z * norm);
    atomicAdd(out + 3, v.w * norm);
}
template <int BM, int BN, int BK, int TM, int TN, bool RELU_A>
__global__ __launch_bounds__(256) void gemm_nt(const float* __restrict__ A,
                                               const float* __restrict__ B,
                                               float* __restrict__ C,
                                               int M, int N, int K) {
    __shared__ float As[BK][BM + 1];
    __shared__ float Bs[BK][BN + 1];
    const int tid = threadIdx.x;
    const int NTX = BN / TN;
    const int tx = tid % NTX;
    const int ty = tid / NTX;
    const int m0 = blockIdx.x * BM;
    const int n0 = blockIdx.y * BN;
    float acc[TM][TN] = {};
    for (int k0 = 0; k0 < K; k0 += BK) {
        for (int idx = tid; idx < BM * BK; idx += 256) {
            int m = idx / BK, k = idx % BK;
            int gm = m0 + m;
            float v = (gm < M) ? A[(long long)gm * K + k0 + k] : 0.0f;
            if (RELU_A) v = fmaxf(v, 0.0f);
            As[k][m] = v;
        }
        for (int idx = tid; idx < BN * BK; idx += 256) {
            int n = idx / BK, k = idx % BK;
            int gn = n0 + n;
            Bs[k][n] = (gn < N) ? B[(long long)gn * K + k0 + k] : 0.0f;
        }
        __syncthreads();
        for (int k = 0; k < BK; ++k) {
            float a[TM], b[TN];
#pragma unroll
            for (int r = 0; r < TM; ++r) a[r] = As[k][ty * TM + r];
#pragma unroll
            for (int c = 0; c < TN; ++c) b[c] = Bs[k][c * NTX + tx];
#pragma unroll
            for (int r = 0; r < TM; ++r)
#pragma unroll
                for (int c = 0; c < TN; ++c) acc[r][c] += a[r] * b[c];
        }
        __syncthreads();
    }
#pragma unroll
    for (int r = 0; r < TM; ++r) {
        int gm = m0 + ty * TM + r;
        if (gm >= M) continue;
#pragma unroll
        for (int c = 0; c < TN; ++c) {
            int gn = n0 + c * NTX + tx;
            if (gn < N) C[(long long)gm * N + gn] = acc[r][c];
        }
    }
}
__global__ __launch_bounds__(256) void gemm_lin(const float* __restrict__ A,
                                                const float* __restrict__ W,
                                                float* __restrict__ C, int M) {
    __shared__ float Ws[16][129];
    __shared__ float As[16][129];
    const int tid = threadIdx.x;
    for (int idx = tid; idx < 16 * 128; idx += 256) Ws[idx >> 7][idx & 127] = W[idx];
    const int m0 = blockIdx.x * 16;
    for (int idx = tid; idx < 16 * 128; idx += 256) {
        int r = idx >> 7, k = idx & 127;
        int gm = m0 + r;
        As[r][k] = (gm < M) ? A[(long long)gm * 128 + k] : 0.0f;
    }
    __syncthreads();
    const int tc = tid & 15, tr = tid >> 4;
    float s = 0.f;
#pragma unroll 8
    for (int k = 0; k < 128; ++k) s += As[tr][k] * Ws[tc][k];
    int gm = m0 + tr;
    if (gm < M) C[gm * 16 + tc] = s;
}

// ---------------- launcher ----------------

static inline size_t align256(size_t x) { return (x + 255) & ~(size_t)255; }

extern "C" void kernel_launch(void* const* d_in, const int* in_sizes, int n_in,
                              void* d_out, int out_size, void* d_ws, size_t ws_size,
                              hipStream_t stream) {
    const float* x    = (const float*)d_in[0];
    const int*   ei   = (const int*)d_in[1];
    const float* W1   = (const float*)d_in[2];
    const float* W2   = (const float*)d_in[3];
    const float* Wlin = (const float*)d_in[4];
    float* out = (float*)d_out;

    const int E = in_sizes[1] / 2;
    const int* src = ei;
    const int* dst = ei + E;

    // workspace layout
    char* ws = (char*)d_ws;
    size_t off = 0;
    float* isd  = (float*)(ws + off); off += align256((size_t)N_NODES * 4);
    float* Wc   = (float*)(ws + off); off += align256(16 * 128 * 4);
    float* bufA = (float*)(ws + off); off += align256((size_t)N_NODES * F_HID * 4);
    float* bufB = (float*)(ws + off); off += align256((size_t)N_NODES * F_HID * 4);
    int*   hist    = (int*)(ws + off); off += align256((size_t)N_NODES * 4);
    int*   rowptr  = (int*)(ws + off); off += align256(((size_t)N_NODES + 1) * 4);
    int*   blksum  = (int*)(ws + off); off += align256(256 * 4);
    int*   csr_src = (int*)(ws + off); off += align256((size_t)E * 4);
    int*   rank    = (int*)(ws + off); off += align256((size_t)E * 4);
    ushort* w1hi   = (ushort*)(ws + off); off += align256((size_t)128 * 512 * 2);
    ushort* w1lo   = (ushort*)(ws + off); off += align256((size_t)128 * 512 * 2);
    const bool use_csr = (off <= ws_size);

    const int nblk_nodes = NSCAN_BLKS;
    const int nblk_edges = (E + 255) / 256;
    const int mtiles = (N_NODES + 63) / 64;

    if (use_csr) {
        unsigned* hb = (unsigned*)bufB;   // [N][64] packed bf16x2 (12.8 MB)
        float*    z  = bufA;              // [N][16] fp32

        // 1. CSR build + normalization (one atomic pass)
        hipMemsetAsync(hist, 0, (size_t)N_NODES * 4, stream);
        k_hist_rank<<<nblk_edges, 256, 0, stream>>>(dst, hist, rank, E);
        k_scan_local<<<nblk_nodes, 256, 0, stream>>>(hist, rowptr, blksum);
        k_scan_blk<<<1, 256, 0, stream>>>(blksum);
        k_finalize<<<nblk_nodes, 256, 0, stream>>>(hist, rowptr, blksum, isd, E);
        k_reorder<<<nblk_edges, 256, 0, stream>>>(src, dst, rank, rowptr, csr_src, E);
        // 2. Wc = Wlin @ W2 ; W1 hi/lo bf16 split (padded K=512)
        k_wc<<<16, 128, 0, stream>>>(W2, Wlin, Wc);
        k_w1split<<<(128 * 512 + 255) / 256, 256, 0, stream>>>(W1, w1hi, w1lo);
        // 3. h1 = x @ W1^T -> bf16 via MFMA (3-pass Dekker split, fp32-equiv accuracy)
        gemm1_mfma<<<mtiles, 256, 0, stream>>>(x, w1hi, w1lo, hb, N_NODES);
        // 4+5. z = relu(A_norm * h1) @ Wc^T   (fused, 2 waves/node)
        k_gather_fused2<<<N_NODES / 2, 256, 0, stream>>>(
            hb, rowptr, csr_src, isd, Wc, z);
        // 6. out = A_norm * z
        k_gather16<<<(N_NODES * 4 + 255) / 256, 256, 0, stream>>>(
            (const float4*)z, rowptr, csr_src, isd, (float4*)out);
    } else {
        // fallback: atomic scatter path (fp32)
        const int nblk_feat = (N_NODES * (F_HID / 4) + 255) / 256;
        const int nblk_scatter = (int)(((long long)E * 32 + 255) / 256);
        k_deg_init<<<(N_NODES + 255) / 256, 256, 0, stream>>>(isd);
        k_deg_count<<<nblk_edges, 256, 0, stream>>>(dst, isd, E);
        k_rsqrt<<<(N_NODES + 255) / 256, 256, 0, stream>>>(isd);
        gemm_nt<64, 128, 20, 4, 8, false>
            <<<dim3(mtiles, 1), 256, 0, stream>>>(x, W1, bufA, N_NODES, F_HID, F_IN);
        k_agg_init<<<nblk_feat, 256, 0, stream>>>((const float4*)bufA, isd, (float4*)bufB);
        k_scatter<<<nblk_scatter, 256, 0, stream>>>((const float4*)bufA, src, dst, isd, bufB, E);
        gemm_nt<64, 128, 16, 4, 8, true>
            <<<dim3(mtiles, 1), 256, 0, stream>>>(bufB, W2, bufA, N_NODES, F_HID, F_HID);
        k_agg_init<<<nblk_feat, 256, 0, stream>>>((const float4*)bufA, isd, (float4*)bufB);
        k_scatter<<<nblk_scatter, 256, 0, stream>>>((const float4*)bufA, src, dst, isd, bufB, E);
        gemm_lin<<<(N_NODES + 15) / 16, 256, 0, stream>>>(bufB, Wlin, out, N_NODES);
    }
}

// Round 3
// 491.890 us; speedup vs baseline: 1.0535x; 1.0373x over previous
//
#include <hip/hip_runtime.h>

#define N_NODES 50000
#define F_IN 500
#define F_HID 128
#define F_OUT 16
#define NSCAN_BLKS ((N_NODES + 255) / 256)   // 196

// ---------------- bf16 helpers (RTNE pack, shift decode) ----------------

__device__ __forceinline__ unsigned bf16_pack2(float a, float b) {
    unsigned ua = __float_as_uint(a);
    unsigned ub = __float_as_uint(b);
    ua = (ua + 0x7fffu + ((ua >> 16) & 1u)) >> 16;
    ub = (ub + 0x7fffu + ((ub >> 16) & 1u)) >> 16;
    return ua | (ub << 16);
}
__device__ __forceinline__ float bf_lo(unsigned v) { return __uint_as_float(v << 16); }
__device__ __forceinline__ float bf_hi(unsigned v) { return __uint_as_float(v & 0xffff0000u); }

__device__ __forceinline__ unsigned bf16_rtne(float a) {
    unsigned u = __float_as_uint(a);
    return (u + 0x7fffu + ((u >> 16) & 1u)) >> 16;
}

// ---------------- CSR build (single atomic pass, round-9 proven) ----------------

__global__ void k_hist_rank(const int* __restrict__ dst, int* __restrict__ hist,
                            int* __restrict__ rank, int E) {
    int e = blockIdx.x * 256 + threadIdx.x;
    if (e < E) rank[e] = atomicAdd(&hist[dst[e]], 1);
}

__global__ __launch_bounds__(256) void k_scan_local(const int* __restrict__ hist,
                                                    int* __restrict__ rowptr,
                                                    int* __restrict__ blksum) {
    __shared__ int s[256];
    const int tid = threadIdx.x;
    const int i = blockIdx.x * 256 + tid;
    int v = (i < N_NODES) ? hist[i] : 0;
    s[tid] = v;
    __syncthreads();
#pragma unroll
    for (int ofs = 1; ofs < 256; ofs <<= 1) {
        int t = (tid >= ofs) ? s[tid - ofs] : 0;
        __syncthreads();
        if (tid >= ofs) s[tid] += t;
        __syncthreads();
    }
    if (i < N_NODES) rowptr[i] = s[tid] - v;
    if (tid == 255) blksum[blockIdx.x] = s[255];
}

__global__ __launch_bounds__(256) void k_scan_blk(int* __restrict__ blksum) {
    __shared__ int s[256];
    const int tid = threadIdx.x;
    int v = (tid < NSCAN_BLKS) ? blksum[tid] : 0;
    s[tid] = v;
    __syncthreads();
#pragma unroll
    for (int ofs = 1; ofs < 256; ofs <<= 1) {
        int t = (tid >= ofs) ? s[tid - ofs] : 0;
        __syncthreads();
        if (tid >= ofs) s[tid] += t;
        __syncthreads();
    }
    if (tid < NSCAN_BLKS) blksum[tid] = s[tid] - v;
}

__global__ void k_finalize(const int* __restrict__ hist, int* __restrict__ rowptr,
                           const int* __restrict__ blksum, float* __restrict__ isd, int E) {
    int i = blockIdx.x * 256 + threadIdx.x;
    if (i < N_NODES) {
        rowptr[i] = rowptr[i] + blksum[i >> 8];
        isd[i] = rsqrtf((float)(hist[i] + 1));  // +1 self-loop
    }
    if (i == 0) rowptr[N_NODES] = E;
}

__global__ void k_reorder(const int* __restrict__ src, const int* __restrict__ dst,
                          const int* __restrict__ rank, const int* __restrict__ rowptr,
                          int* __restrict__ csr_src, int E) {
    int e = blockIdx.x * 256 + threadIdx.x;
    if (e >= E) return;
    csr_src[rowptr[dst[e]] + rank[e]] = src[e];
}

// ---------------- Wc = Wlin @ W2  [16,128] ----------------

__global__ void k_wc(const float* __restrict__ W2, const float* __restrict__ Wlin,
                     float* __restrict__ Wc) {
    const int c = blockIdx.x;       // 0..15
    const int j = threadIdx.x;      // 0..127
    const float* wl = Wlin + c * 128;
    float acc = 0.f;
#pragma unroll 4
    for (int k = 0; k < 128; ++k) acc += wl[k] * W2[k * 128 + j];
    Wc[c * 128 + j] = acc;
}

// ---------------- W1 pack: fragment-major bf16 hi/lo, padded K 500->512 ----------------
// Layout: wpk[kt][f][h][lane][8]  (ushort), h=0 hi, h=1 lo.
// For (kt,f,lane,j): n = 16f + (lane&15), k = kt*32 + (lane>>4)*8 + j.
// A wave's B-fragment load for (kt,f,h) is then 64 lanes x 16 B fully contiguous.

__global__ __launch_bounds__(256) void k_w1pack(const float* __restrict__ W1,
                                                ushort* __restrict__ wpk) {
    int t = blockIdx.x * 256 + threadIdx.x;   // (kt*8+f)*64 + lane ; 8192 total
    if (t >= 8192) return;
    const int lane = t & 63;
    const int fkt = t >> 6;
    const int f = fkt & 7;
    const int kt = fkt >> 3;
    const int n = (f << 4) + (lane & 15);
    const int kb = (kt << 5) + ((lane >> 4) << 3);
    ushort h8[8], l8[8];
#pragma unroll
    for (int j = 0; j < 8; ++j) {
        const int k = kb + j;
        float v = (k < F_IN) ? W1[n * F_IN + k] : 0.f;
        unsigned h = bf16_rtne(v);
        float fh = __uint_as_float(h << 16);
        unsigned l = bf16_rtne(v - fh);      // Dekker residual, exact in fp32
        h8[j] = (ushort)h;
        l8[j] = (ushort)l;
    }
    const size_t base = ((size_t)fkt << 10);         // (kt*8+f)*1024 elements
    *(uint4*)(wpk + base + (lane << 3))       = *(const uint4*)h8;
    *(uint4*)(wpk + base + 512 + (lane << 3)) = *(const uint4*)l8;
}

// ---------------- GEMM1 via MFMA + LDS-staged B: hb[M,128](bf16) = A @ W1^T ----------------
// 3-pass Dekker split (Ahi*Whi + Alo*Whi + Ahi*Wlo) = fp32-equivalent accuracy.
// B tile (16 KB/kt) staged global->reg->LDS (issue-early/write-late, T14),
// double-buffered, ONE barrier per kt. Plain HIP only (no global_load_lds —
// the addrspace-cast idiom was the only infra-risky construct in round 2).
// A: direct global + distance-1 register prefetch.

typedef __attribute__((ext_vector_type(8))) short s16x8;
typedef __attribute__((ext_vector_type(4))) float f32x4;

__global__ __launch_bounds__(256) void gemm1_mfma3(const float* __restrict__ A,
                                                   const ushort* __restrict__ wpk,
                                                   unsigned* __restrict__ hb, int M) {
    __shared__ __align__(16) ushort Bs[2][8192];   // 2 x 16 KB

    const int tid = threadIdx.x;
    const int lane = tid & 63;
    const int wave = tid >> 6;                // 0..3
    const int jcol = lane & 15;
    const int kgrp = lane >> 4;
    const int klo  = kgrp << 3;

    const int m0  = blockIdx.x * 64 + wave * 16;
    const int arw = m0 + jcol;
    const float* arow = A + (size_t)((arw < M) ? arw : (M - 1)) * F_IN;

    const uint4* tb = (const uint4*)wpk;      // tile kt = tb[kt*1024 .. +1023]

    const float4 zf4 = make_float4(0.f, 0.f, 0.f, 0.f);
    float4 ca0 = zf4, ca1 = zf4;
    uint4 st[4];

    // ---- prologue: stage tile 0, load A(0), issue tile-1 global loads ----
#pragma unroll
    for (int c = 0; c < 4; ++c) st[c] = tb[(c << 8) + tid];
#pragma unroll
    for (int c = 0; c < 4; ++c) *(uint4*)&Bs[0][((c << 8) + tid) << 3] = st[c];
    {
        ca0 = *(const float4*)(arow + klo);        // kt=0: klo+8 <= 32 < 500
        ca1 = *(const float4*)(arow + klo + 4);
    }
#pragma unroll
    for (int c = 0; c < 4; ++c) st[c] = tb[1024 + (c << 8) + tid];
    __syncthreads();   // tile 0 visible

    f32x4 acc[8] = {};

    for (int kt = 0; kt < 16; ++kt) {
        const int cb = kt & 1, nb = (kt + 1) & 1;

        // ---- prefetch next A into registers ----
        float4 na0 = zf4, na1 = zf4;
        if (kt + 1 < 16) {
            const int k = ((kt + 1) << 5) + klo;
            if (k + 8 <= F_IN) {
                na0 = *(const float4*)(arow + k);
                na1 = *(const float4*)(arow + k + 4);
            } else {
                float tmp[8];
#pragma unroll
                for (int i = 0; i < 8; ++i) tmp[i] = (k + i < F_IN) ? arow[k + i] : 0.f;
                na0 = make_float4(tmp[0], tmp[1], tmp[2], tmp[3]);
                na1 = make_float4(tmp[4], tmp[5], tmp[6], tmp[7]);
            }
        }

        // ---- Dekker split current A ----
        const float av[8] = {ca0.x, ca0.y, ca0.z, ca0.w, ca1.x, ca1.y, ca1.z, ca1.w};
        s16x8 ahi, alo;
#pragma unroll
        for (int i = 0; i < 8; ++i) {
            unsigned h = bf16_rtne(av[i]);
            float fh = __uint_as_float(h << 16);
            unsigned l = bf16_rtne(av[i] - fh);
            ahi[i] = (short)h;
            alo[i] = (short)l;
        }

        // ---- 8 column fragments from LDS x 3 MFMA passes ----
#pragma unroll
        for (int f = 0; f < 8; ++f) {
            const s16x8 bh = *(const s16x8*)&Bs[cb][(f << 10) + (lane << 3)];
            const s16x8 bl = *(const s16x8*)&Bs[cb][(f << 10) + 512 + (lane << 3)];
            acc[f] = __builtin_amdgcn_mfma_f32_16x16x32_bf16(ahi, bh, acc[f], 0, 0, 0);
            acc[f] = __builtin_amdgcn_mfma_f32_16x16x32_bf16(alo, bh, acc[f], 0, 0, 0);
            acc[f] = __builtin_amdgcn_mfma_f32_16x16x32_bf16(ahi, bl, acc[f], 0, 0, 0);
        }

        // ---- write-late: staged regs (tile kt+1) -> LDS nb; issue tile kt+2 ----
        if (kt + 1 < 16) {
#pragma unroll
            for (int c = 0; c < 4; ++c) *(uint4*)&Bs[nb][((c << 8) + tid) << 3] = st[c];
            if (kt + 2 < 16) {
#pragma unroll
                for (int c = 0; c < 4; ++c) st[c] = tb[((kt + 2) << 10) + (c << 8) + tid];
            }
        }

        ca0 = na0;
        ca1 = na1;
        __syncthreads();   // tile kt+1 visible; my cb reads drained for kt+1's write
    }

    // ---- epilogue: pack adjacent features via shfl (round-1 proven) ----
    const int orow = m0 + (kgrp << 2);
#pragma unroll
    for (int f = 0; f < 8; ++f) {
#pragma unroll
        for (int r = 0; r < 4; ++r) {
            float v = acc[f][r];
            float o = __shfl_xor(v, 1, 64);
            if (!(jcol & 1)) {
                const int m = orow + r;
                if (m < M)
                    hb[(size_t)m * 64 + (f << 3) + (jcol >> 1)] = bf16_pack2(v, o);
            }
        }
    }
}

// ---------------- fused gather + zlin, TWO waves per node (round-9 proven) ----------------

__device__ __forceinline__ void gather_range(const unsigned* __restrict__ hh,
                                             const int* __restrict__ csr_src,
                                             const float* __restrict__ isd,
                                             float si, int lane, int e, int end,
                                             float& accx, float& accy) {
    int s[8], t[8];
    bool have = (e + 8 <= end);
    if (have) {
#pragma unroll
        for (int i = 0; i < 8; ++i) s[i] = csr_src[e + i];
    }
    while (have) {
        unsigned v[8];
        float w[8];
#pragma unroll
        for (int i = 0; i < 8; ++i) v[i] = hh[(size_t)s[i] * 64 + lane];
#pragma unroll
        for (int i = 0; i < 8; ++i) w[i] = isd[s[i]];
        const int ne = e + 8;
        const bool nhave = (ne + 8 <= end);
        if (nhave) {
#pragma unroll
            for (int i = 0; i < 8; ++i) t[i] = csr_src[ne + i];
        }
#pragma unroll
        for (int i = 0; i < 8; ++i) {
            const float wi = w[i] * si;
            accx += wi * bf_lo(v[i]);
            accy += wi * bf_hi(v[i]);
        }
#pragma unroll
        for (int i = 0; i < 8; ++i) s[i] = t[i];
        e = ne;
        have = nhave;
    }
    for (; e < end; ++e) {
        const int ss = csr_src[e];
        const float wi = isd[ss] * si;
        const unsigned v = hh[(size_t)ss * 64 + lane];
        accx += wi * bf_lo(v);
        accy += wi * bf_hi(v);
    }
}

__global__ __launch_bounds__(256) void k_gather_fused2(const unsigned* __restrict__ hh,
                                                       const int* __restrict__ rowptr,
                                                       const int* __restrict__ csr_src,
                                                       const float* __restrict__ isd,
                                                       const float* __restrict__ Wc,
                                                       float* __restrict__ z) {
    __shared__ float2 part[2][64];
    const int tid = threadIdx.x;
    const int lane = tid & 63;
    const int waveid = tid >> 6;         // 0..3
    const int slot = waveid >> 1;        // node slot 0..1
    const int half = waveid & 1;         // 0 = primary, 1 = secondary
    const int node = (blockIdx.x << 1) + slot;   // < 50000 always (grid=25000)

    const float si = isd[node];
    const int e0 = rowptr[node], e1 = rowptr[node + 1];
    const int mid = e0 + ((e1 - e0) >> 1);

    float accx = 0.f, accy = 0.f;
    if (half == 0) {
        const unsigned a = hh[(size_t)node * 64 + lane];   // self-loop
        accx = bf_lo(a) * si * si;
        accy = bf_hi(a) * si * si;
        gather_range(hh, csr_src, isd, si, lane, e0, mid, accx, accy);
    } else {
        gather_range(hh, csr_src, isd, si, lane, mid, e1, accx, accy);
        part[slot][lane] = make_float2(accx, accy);
    }
    __syncthreads();
    if (half == 1) return;

    const float2 pb = part[slot][lane];
    accx += pb.x;
    accy += pb.y;

    // relu + Wc dot + wave reduction
    const float rx = fmaxf(accx, 0.f), ry = fmaxf(accy, 0.f);
    float p[16];
#pragma unroll
    for (int c = 0; c < 16; ++c) {
        const float2 wc = *(const float2*)(Wc + c * 128 + (lane << 1));
        p[c] = rx * wc.x + ry * wc.y;
    }
#pragma unroll
    for (int m = 1; m < 64; m <<= 1) {
#pragma unroll
        for (int c = 0; c < 16; ++c) p[c] += __shfl_xor(p[c], m, 64);
    }
    if (lane == 0) {
        float* zr = z + (size_t)node * 16;
        *(float4*)(zr + 0)  = make_float4(p[0],  p[1],  p[2],  p[3]);
        *(float4*)(zr + 4)  = make_float4(p[4],  p[5],  p[6],  p[7]);
        *(float4*)(zr + 8)  = make_float4(p[8],  p[9],  p[10], p[11]);
        *(float4*)(zr + 12) = make_float4(p[12], p[13], p[14], p[15]);
    }
}

// ---------------- gather (16-wide): 4 threads per node ----------------

__global__ __launch_bounds__(256) void k_gather16(const float4* __restrict__ z4,
                                                  const int* __restrict__ rowptr,
                                                  const int* __restrict__ csr_src,
                                                  const float* __restrict__ isd,
                                                  float4* __restrict__ out4) {
    int t = blockIdx.x * 256 + threadIdx.x;
    int n = t >> 2, q = t & 3;
    if (n >= N_NODES) return;
    const float si = isd[n];
    float4 a = z4[(size_t)n * 4 + q];
    float4 acc;
    acc.x = a.x * si * si; acc.y = a.y * si * si;
    acc.z = a.z * si * si; acc.w = a.w * si * si;
    int e = rowptr[n];
    const int end = rowptr[n + 1];
    for (; e + 4 <= end; e += 4) {
        int s0 = csr_src[e],     s1 = csr_src[e + 1];
        int s2 = csr_src[e + 2], s3 = csr_src[e + 3];
        float w0 = isd[s0] * si, w1 = isd[s1] * si;
        float w2 = isd[s2] * si, w3 = isd[s3] * si;
        float4 v0 = z4[(size_t)s0 * 4 + q];
        float4 v1 = z4[(size_t)s1 * 4 + q];
        float4 v2 = z4[(size_t)s2 * 4 + q];
        float4 v3 = z4[(size_t)s3 * 4 + q];
        acc.x += w0 * v0.x; acc.y += w0 * v0.y; acc.z += w0 * v0.z; acc.w += w0 * v0.w;
        acc.x += w1 * v1.x; acc.y += w1 * v1.y; acc.z += w1 * v1.z; acc.w += w1 * v1.w;
        acc.x += w2 * v2.x; acc.y += w2 * v2.y; acc.z += w2 * v2.z; acc.w += w2 * v2.w;
        acc.x += w3 * v3.x; acc.y += w3 * v3.y; acc.z += w3 * v3.z; acc.w += w3 * v3.w;
    }
    for (; e < end; ++e) {
        int s = csr_src[e];
        float w = isd[s] * si;
        float4 v = z4[(size_t)s * 4 + q];
        acc.x += w * v.x; acc.y += w * v.y; acc.z += w * v.z; acc.w += w * v.w;
    }
    out4[(size_t)n * 4 + q] = acc;
}

// ---------------- fallback (round-1 atomic path, all fp32) ----------------

__global__ void k_deg_init(float* __restrict__ deg) {
    int i = blockIdx.x * 256 + threadIdx.x;
    if (i < N_NODES) deg[i] = 1.0f;
}
__global__ void k_deg_count(const int* __restrict__ dst, float* __restrict__ deg, int E) {
    int e = blockIdx.x * 256 + threadIdx.x;
    if (e < E) atomicAdd(&deg[dst[e]], 1.0f);
}
__global__ void k_rsqrt(float* __restrict__ deg) {
    int i = blockIdx.x * 256 + threadIdx.x;
    if (i < N_NODES) deg[i] = rsqrtf(deg[i]);
}
__global__ void k_agg_init(const float4* __restrict__ h, const float* __restrict__ isd,
                           float4* __restrict__ agg) {
    int t = blockIdx.x * 256 + threadIdx.x;
    if (t < N_NODES * (F_HID / 4)) {
        int row = t >> 5;
        float s = isd[row];
        s = s * s;
        float4 v = h[t];
        v.x *= s; v.y *= s; v.z *= s; v.w *= s;
        agg[t] = v;
    }
}
__global__ void k_scatter(const float4* __restrict__ h, const int* __restrict__ src,
                          const int* __restrict__ dst, const float* __restrict__ isd,
                          float* __restrict__ agg, int E) {
    int t = blockIdx.x * 256 + threadIdx.x;
    int e = t >> 5, q = t & 31;
    if (e >= E) return;
    int s = src[e], d = dst[e];
    float norm = isd[s] * isd[d];
    float4 v = h[(long long)s * 32 + q];
    float* out = agg + (long long)d * F_HID + q * 4;
    atomicAdd(out + 0, v.x * norm);
    atomicAdd(out + 1, v.y * norm);
    atomicAdd(out + 2, v.z * norm);
    atomicAdd(out + 3, v.w * norm);
}
template <int BM, int BN, int BK, int TM, int TN, bool RELU_A>
__global__ __launch_bounds__(256) void gemm_nt(const float* __restrict__ A,
                                               const float* __restrict__ B,
                                               float* __restrict__ C,
                                               int M, int N, int K) {
    __shared__ float As[BK][BM + 1];
    __shared__ float Bs[BK][BN + 1];
    const int tid = threadIdx.x;
    const int NTX = BN / TN;
    const int tx = tid % NTX;
    const int ty = tid / NTX;
    const int m0 = blockIdx.x * BM;
    const int n0 = blockIdx.y * BN;
    float acc[TM][TN] = {};
    for (int k0 = 0; k0 < K; k0 += BK) {
        for (int idx = tid; idx < BM * BK; idx += 256) {
            int m = idx / BK, k = idx % BK;
            int gm = m0 + m;
            float v = (gm < M) ? A[(long long)gm * K + k0 + k] : 0.0f;
            if (RELU_A) v = fmaxf(v, 0.0f);
            As[k][m] = v;
        }
        for (int idx = tid; idx < BN * BK; idx += 256) {
            int n = idx / BK, k = idx % BK;
            int gn = n0 + n;
            Bs[k][n] = (gn < N) ? B[(long long)gn * K + k0 + k] : 0.0f;
        }
        __syncthreads();
        for (int k = 0; k < BK; ++k) {
            float a[TM], b[TN];
#pragma unroll
            for (int r = 0; r < TM; ++r) a[r] = As[k][ty * TM + r];
#pragma unroll
            for (int c = 0; c < TN; ++c) b[c] = Bs[k][c * NTX + tx];
#pragma unroll
            for (int r = 0; r < TM; ++r)
#pragma unroll
                for (int c = 0; c < TN; ++c) acc[r][c] += a[r] * b[c];
        }
        __syncthreads();
    }
#pragma unroll
    for (int r = 0; r < TM; ++r) {
        int gm = m0 + ty * TM + r;
        if (gm >= M) continue;
#pragma unroll
        for (int c = 0; c < TN; ++c) {
            int gn = n0 + c * NTX + tx;
            if (gn < N) C[(long long)gm * N + gn] = acc[r][c];
        }
    }
}
__global__ __launch_bounds__(256) void gemm_lin(const float* __restrict__ A,
                                                const float* __restrict__ W,
                                                float* __restrict__ C, int M) {
    __shared__ float Ws[16][129];
    __shared__ float As[16][129];
    const int tid = threadIdx.x;
    for (int idx = tid; idx < 16 * 128; idx += 256) Ws[idx >> 7][idx & 127] = W[idx];
    const int m0 = blockIdx.x * 16;
    for (int idx = tid; idx < 16 * 128; idx += 256) {
        int r = idx >> 7, k = idx & 127;
        int gm = m0 + r;
        As[r][k] = (gm < M) ? A[(long long)gm * 128 + k] : 0.0f;
    }
    __syncthreads();
    const int tc = tid & 15, tr = tid >> 4;
    float s = 0.f;
#pragma unroll 8
    for (int k = 0; k < 128; ++k) s += As[tr][k] * Ws[tc][k];
    int gm = m0 + tr;
    if (gm < M) C[gm * 16 + tc] = s;
}

// ---------------- launcher ----------------

static inline size_t align256(size_t x) { return (x + 255) & ~(size_t)255; }

extern "C" void kernel_launch(void* const* d_in, const int* in_sizes, int n_in,
                              void* d_out, int out_size, void* d_ws, size_t ws_size,
                              hipStream_t stream) {
    const float* x    = (const float*)d_in[0];
    const int*   ei   = (const int*)d_in[1];
    const float* W1   = (const float*)d_in[2];
    const float* W2   = (const float*)d_in[3];
    const float* Wlin = (const float*)d_in[4];
    float* out = (float*)d_out;

    const int E = in_sizes[1] / 2;
    const int* src = ei;
    const int* dst = ei + E;

    // workspace layout
    char* ws = (char*)d_ws;
    size_t off = 0;
    float* isd  = (float*)(ws + off); off += align256((size_t)N_NODES * 4);
    float* Wc   = (float*)(ws + off); off += align256(16 * 128 * 4);
    float* bufA = (float*)(ws + off); off += align256((size_t)N_NODES * F_HID * 4);
    float* bufB = (float*)(ws + off); off += align256((size_t)N_NODES * F_HID * 4);
    int*   hist    = (int*)(ws + off); off += align256((size_t)N_NODES * 4);
    int*   rowptr  = (int*)(ws + off); off += align256(((size_t)N_NODES + 1) * 4);
    int*   blksum  = (int*)(ws + off); off += align256(256 * 4);
    int*   csr_src = (int*)(ws + off); off += align256((size_t)E * 4);
    int*   rank    = (int*)(ws + off); off += align256((size_t)E * 4);
    ushort* wpk    = (ushort*)(ws + off); off += align256((size_t)16 * 8192 * 2);  // 256 KB
    const bool use_csr = (off <= ws_size);

    const int nblk_nodes = NSCAN_BLKS;
    const int nblk_edges = (E + 255) / 256;
    const int mtiles = (N_NODES + 63) / 64;

    if (use_csr) {
        unsigned* hb = (unsigned*)bufB;   // [N][64] packed bf16x2 (12.8 MB)
        float*    z  = bufA;              // [N][16] fp32

        // 1. CSR build + normalization (one atomic pass)
        hipMemsetAsync(hist, 0, (size_t)N_NODES * 4, stream);
        k_hist_rank<<<nblk_edges, 256, 0, stream>>>(dst, hist, rank, E);
        k_scan_local<<<nblk_nodes, 256, 0, stream>>>(hist, rowptr, blksum);
        k_scan_blk<<<1, 256, 0, stream>>>(blksum);
        k_finalize<<<nblk_nodes, 256, 0, stream>>>(hist, rowptr, blksum, isd, E);
        k_reorder<<<nblk_edges, 256, 0, stream>>>(src, dst, rank, rowptr, csr_src, E);
        // 2. Wc = Wlin @ W2 ; W1 fragment-major bf16 hi/lo pack (padded K=512)
        k_wc<<<16, 128, 0, stream>>>(W2, Wlin, Wc);
        k_w1pack<<<32, 256, 0, stream>>>(W1, wpk);
        // 3. h1 = x @ W1^T -> bf16 via MFMA (reg-staged LDS dbuf B, A prefetch)
        gemm1_mfma3<<<mtiles, 256, 0, stream>>>(x, wpk, hb, N_NODES);
        // 4+5. z = relu(A_norm * h1) @ Wc^T   (fused, 2 waves/node)
        k_gather_fused2<<<N_NODES / 2, 256, 0, stream>>>(
            hb, rowptr, csr_src, isd, Wc, z);
        // 6. out = A_norm * z
        k_gather16<<<(N_NODES * 4 + 255) / 256, 256, 0, stream>>>(
            (const float4*)z, rowptr, csr_src, isd, (float4*)out);
    } else {
        // fallback: atomic scatter path (fp32)
        const int nblk_feat = (N_NODES * (F_HID / 4) + 255) / 256;
        const int nblk_scatter = (int)(((long long)E * 32 + 255) / 256);
        k_deg_init<<<(N_NODES + 255) / 256, 256, 0, stream>>>(isd);
        k_deg_count<<<nblk_edges, 256, 0, stream>>>(dst, isd, E);
        k_rsqrt<<<(N_NODES + 255) / 256, 256, 0, stream>>>(isd);
        gemm_nt<64, 128, 20, 4, 8, false>
            <<<dim3(mtiles, 1), 256, 0, stream>>>(x, W1, bufA, N_NODES, F_HID, F_IN);
        k_agg_init<<<nblk_feat, 256, 0, stream>>>((const float4*)bufA, isd, (float4*)bufB);
        k_scatter<<<nblk_scatter, 256, 0, stream>>>((const float4*)bufA, src, dst, isd, bufB, E);
        gemm_nt<64, 128, 16, 4, 8, true>
            <<<dim3(mtiles, 1), 256, 0, stream>>>(bufB, W2, bufA, N_NODES, F_HID, F_HID);
        k_agg_init<<<nblk_feat, 256, 0, stream>>>((const float4*)bufA, isd, (float4*)bufB);
        k_scatter<<<nblk_scatter, 256, 0, stream>>>((const float4*)bufA, src, dst, isd, bufB, E);
        gemm_lin<<<(N_NODES + 15) / 16, 256, 0, stream>>>(bufB, Wlin, out, N_NODES);
    }
}

// Round 4
// 436.970 us; speedup vs baseline: 1.1859x; 1.1257x over previous
//
#include <hip/hip_runtime.h>

#define N_NODES 50000
#define F_IN 500
#define F_HID 128
#define F_OUT 16
#define NSCAN_BLKS ((N_NODES + 255) / 256)   // 196

// ---------------- bf16 helpers (RTNE pack, shift decode) ----------------

__device__ __forceinline__ unsigned bf16_pack2(float a, float b) {
    unsigned ua = __float_as_uint(a);
    unsigned ub = __float_as_uint(b);
    ua = (ua + 0x7fffu + ((ua >> 16) & 1u)) >> 16;
    ub = (ub + 0x7fffu + ((ub >> 16) & 1u)) >> 16;
    return ua | (ub << 16);
}
__device__ __forceinline__ float bf_lo(unsigned v) { return __uint_as_float(v << 16); }
__device__ __forceinline__ float bf_hi(unsigned v) { return __uint_as_float(v & 0xffff0000u); }

__device__ __forceinline__ unsigned bf16_rtne(float a) {
    unsigned u = __float_as_uint(a);
    return (u + 0x7fffu + ((u >> 16) & 1u)) >> 16;
}

// ---------------- CSR build (single atomic pass, round-9 proven) ----------------

__global__ void k_hist_rank(const int* __restrict__ dst, int* __restrict__ hist,
                            int* __restrict__ rank, int E) {
    int e = blockIdx.x * 256 + threadIdx.x;
    if (e < E) rank[e] = atomicAdd(&hist[dst[e]], 1);
}

__global__ __launch_bounds__(256) void k_scan_local(const int* __restrict__ hist,
                                                    int* __restrict__ rowptr,
                                                    int* __restrict__ blksum) {
    __shared__ int s[256];
    const int tid = threadIdx.x;
    const int i = blockIdx.x * 256 + tid;
    int v = (i < N_NODES) ? hist[i] : 0;
    s[tid] = v;
    __syncthreads();
#pragma unroll
    for (int ofs = 1; ofs < 256; ofs <<= 1) {
        int t = (tid >= ofs) ? s[tid - ofs] : 0;
        __syncthreads();
        if (tid >= ofs) s[tid] += t;
        __syncthreads();
    }
    if (i < N_NODES) rowptr[i] = s[tid] - v;
    if (tid == 255) blksum[blockIdx.x] = s[255];
}

__global__ __launch_bounds__(256) void k_scan_blk(int* __restrict__ blksum) {
    __shared__ int s[256];
    const int tid = threadIdx.x;
    int v = (tid < NSCAN_BLKS) ? blksum[tid] : 0;
    s[tid] = v;
    __syncthreads();
#pragma unroll
    for (int ofs = 1; ofs < 256; ofs <<= 1) {
        int t = (tid >= ofs) ? s[tid - ofs] : 0;
        __syncthreads();
        if (tid >= ofs) s[tid] += t;
        __syncthreads();
    }
    if (tid < NSCAN_BLKS) blksum[tid] = s[tid] - v;
}

__global__ void k_finalize(const int* __restrict__ hist, int* __restrict__ rowptr,
                           const int* __restrict__ blksum, float* __restrict__ isd, int E) {
    int i = blockIdx.x * 256 + threadIdx.x;
    if (i < N_NODES) {
        rowptr[i] = rowptr[i] + blksum[i >> 8];
        isd[i] = rsqrtf((float)(hist[i] + 1));  // +1 self-loop
    }
    if (i == 0) rowptr[N_NODES] = E;
}

__global__ void k_reorder(const int* __restrict__ src, const int* __restrict__ dst,
                          const int* __restrict__ rank, const int* __restrict__ rowptr,
                          int* __restrict__ csr_src, int E) {
    int e = blockIdx.x * 256 + threadIdx.x;
    if (e >= E) return;
    csr_src[rowptr[dst[e]] + rank[e]] = src[e];
}

// ---------------- Wc = Wlin @ W2  [16,128] ----------------

__global__ void k_wc(const float* __restrict__ W2, const float* __restrict__ Wlin,
                     float* __restrict__ Wc) {
    const int c = blockIdx.x;       // 0..15
    const int j = threadIdx.x;      // 0..127
    const float* wl = Wlin + c * 128;
    float acc = 0.f;
#pragma unroll 4
    for (int k = 0; k < 128; ++k) acc += wl[k] * W2[k * 128 + j];
    Wc[c * 128 + j] = acc;
}

// ---------------- W1 pack: fragment-major bf16 hi/lo, padded K 500->512 ----------------
// Layout: wpk[kt][f][h][lane][8]  (ushort), h=0 hi, h=1 lo.
// For (kt,f,lane,j): n = 16f + (lane&15), k = kt*32 + (lane>>4)*8 + j.
// A wave's B-fragment load for (kt,f,h) is then 64 lanes x 16 B fully contiguous,
// and the glds staging order (lane l -> base + l*16B) matches it exactly.

__global__ __launch_bounds__(256) void k_w1pack(const float* __restrict__ W1,
                                                ushort* __restrict__ wpk) {
    int t = blockIdx.x * 256 + threadIdx.x;   // (kt*8+f)*64 + lane ; 8192 total
    if (t >= 8192) return;
    const int lane = t & 63;
    const int fkt = t >> 6;
    const int f = fkt & 7;
    const int kt = fkt >> 3;
    const int n = (f << 4) + (lane & 15);
    const int kb = (kt << 5) + ((lane >> 4) << 3);
    ushort h8[8], l8[8];
#pragma unroll
    for (int j = 0; j < 8; ++j) {
        const int k = kb + j;
        float v = (k < F_IN) ? W1[n * F_IN + k] : 0.f;
        unsigned h = bf16_rtne(v);
        float fh = __uint_as_float(h << 16);
        unsigned l = bf16_rtne(v - fh);      // Dekker residual, exact in fp32
        h8[j] = (ushort)h;
        l8[j] = (ushort)l;
    }
    const size_t base = ((size_t)fkt << 10);         // (kt*8+f)*1024 elements
    *(uint4*)(wpk + base + (lane << 3))       = *(const uint4*)h8;
    *(uint4*)(wpk + base + 512 + (lane << 3)) = *(const uint4*)l8;
}

// ---------------- GEMM1 via MFMA + glds-staged B: hb[M,128](bf16) = A @ W1^T ----------------
// 3-pass Dekker split (Ahi*Whi + Alo*Whi + Ahi*Wlo) = fp32-equivalent accuracy.
// B tile (16 KB/kt) staged via __builtin_amdgcn_global_load_lds width=16
// (ZERO staging VGPRs — round-3's reg-staged variant spilled st[4] to scratch:
// WRITE_SIZE 12.5->158 MB, kernel became spill-traffic-bound at 120 us).
// Double-buffered, one barrier per kt (m97 structure). A: direct global +
// distance-1 register prefetch.

typedef __attribute__((ext_vector_type(8))) short s16x8;
typedef __attribute__((ext_vector_type(4))) float f32x4;

typedef const __attribute__((address_space(1))) unsigned u32_glb;
typedef __attribute__((address_space(3))) unsigned u32_lds;

__device__ __forceinline__ void glds16(const void* g, void* l) {
    __builtin_amdgcn_global_load_lds((u32_glb*)g, (u32_lds*)l, 16, 0, 0);
}

__global__ __launch_bounds__(256) void gemm1_mfma4(const float* __restrict__ A,
                                                   const ushort* __restrict__ wpk,
                                                   unsigned* __restrict__ hb, int M) {
    __shared__ __align__(16) ushort Bs[2][8192];   // 2 x 16 KB

    const int tid = threadIdx.x;
    const int lane = tid & 63;
    const int wave = tid >> 6;                // 0..3
    const int jcol = lane & 15;
    const int kgrp = lane >> 4;
    const int klo  = kgrp << 3;

    const int m0  = blockIdx.x * 64 + wave * 16;
    const int arw = m0 + jcol;
    const float* arow = A + (size_t)((arw < M) ? arw : (M - 1)) * F_IN;

    // wave-uniform LDS dest + per-lane contiguous global src (glds: dst + lane*16)
#define ISSUE_TILE(KT, B)                                                        \
    {                                                                            \
        const ushort* tb_ = wpk + ((size_t)(KT) << 13);                          \
        _Pragma("unroll") for (int c_ = 0; c_ < 4; ++c_) {                       \
            glds16(tb_ + ((c_ * 256 + wave * 64 + lane) << 3),                   \
                   &Bs[B][(c_ * 256 + wave * 64) << 3]);                         \
        }                                                                        \
    }

    const float4 zf4 = make_float4(0.f, 0.f, 0.f, 0.f);
    float4 ca0 = zf4, ca1 = zf4;

    // ---- prologue: issue tile 0, load A(0) ----
    ISSUE_TILE(0, 0);
    ca0 = *(const float4*)(arow + klo);        // kt=0: klo+8 <= 32 < 500
    ca1 = *(const float4*)(arow + klo + 4);
    __syncthreads();   // barrier drains vmcnt -> tile 0 visible

    f32x4 acc[8] = {};

    for (int kt = 0; kt < 16; ++kt) {
        const int cb = kt & 1, nb = (kt + 1) & 1;

        // ---- issue next B tile (async, overlaps this kt's compute) + prefetch next A ----
        float4 na0 = zf4, na1 = zf4;
        if (kt + 1 < 16) {
            ISSUE_TILE(kt + 1, nb);
            const int k = ((kt + 1) << 5) + klo;
            if (k + 8 <= F_IN) {
                na0 = *(const float4*)(arow + k);
                na1 = *(const float4*)(arow + k + 4);
            } else {
                float tmp[8];
#pragma unroll
                for (int i = 0; i < 8; ++i) tmp[i] = (k + i < F_IN) ? arow[k + i] : 0.f;
                na0 = make_float4(tmp[0], tmp[1], tmp[2], tmp[3]);
                na1 = make_float4(tmp[4], tmp[5], tmp[6], tmp[7]);
            }
        }

        // ---- Dekker split current A ----
        const float av[8] = {ca0.x, ca0.y, ca0.z, ca0.w, ca1.x, ca1.y, ca1.z, ca1.w};
        s16x8 ahi, alo;
#pragma unroll
        for (int i = 0; i < 8; ++i) {
            unsigned h = bf16_rtne(av[i]);
            float fh = __uint_as_float(h << 16);
            unsigned l = bf16_rtne(av[i] - fh);
            ahi[i] = (short)h;
            alo[i] = (short)l;
        }

        // ---- 8 column fragments from LDS x 3 MFMA passes ----
#pragma unroll
        for (int f = 0; f < 8; ++f) {
            const s16x8 bh = *(const s16x8*)&Bs[cb][(f << 10) + (lane << 3)];
            const s16x8 bl = *(const s16x8*)&Bs[cb][(f << 10) + 512 + (lane << 3)];
            acc[f] = __builtin_amdgcn_mfma_f32_16x16x32_bf16(ahi, bh, acc[f], 0, 0, 0);
            acc[f] = __builtin_amdgcn_mfma_f32_16x16x32_bf16(alo, bh, acc[f], 0, 0, 0);
            acc[f] = __builtin_amdgcn_mfma_f32_16x16x32_bf16(ahi, bl, acc[f], 0, 0, 0);
        }

        ca0 = na0;
        ca1 = na1;
        __syncthreads();   // tile kt+1 staged; buffer cb free for next issue
    }
#undef ISSUE_TILE

    // ---- epilogue: pack adjacent features via shfl (round-1 proven) ----
    const int orow = m0 + (kgrp << 2);
#pragma unroll
    for (int f = 0; f < 8; ++f) {
#pragma unroll
        for (int r = 0; r < 4; ++r) {
            float v = acc[f][r];
            float o = __shfl_xor(v, 1, 64);
            if (!(jcol & 1)) {
                const int m = orow + r;
                if (m < M)
                    hb[(size_t)m * 64 + (f << 3) + (jcol >> 1)] = bf16_pack2(v, o);
            }
        }
    }
}

// ---------------- fused gather + zlin, TWO waves per node (round-9 proven) ----------------

__device__ __forceinline__ void gather_range(const unsigned* __restrict__ hh,
                                             const int* __restrict__ csr_src,
                                             const float* __restrict__ isd,
                                             float si, int lane, int e, int end,
                                             float& accx, float& accy) {
    int s[8], t[8];
    bool have = (e + 8 <= end);
    if (have) {
#pragma unroll
        for (int i = 0; i < 8; ++i) s[i] = csr_src[e + i];
    }
    while (have) {
        unsigned v[8];
        float w[8];
#pragma unroll
        for (int i = 0; i < 8; ++i) v[i] = hh[(size_t)s[i] * 64 + lane];
#pragma unroll
        for (int i = 0; i < 8; ++i) w[i] = isd[s[i]];
        const int ne = e + 8;
        const bool nhave = (ne + 8 <= end);
        if (nhave) {
#pragma unroll
            for (int i = 0; i < 8; ++i) t[i] = csr_src[ne + i];
        }
#pragma unroll
        for (int i = 0; i < 8; ++i) {
            const float wi = w[i] * si;
            accx += wi * bf_lo(v[i]);
            accy += wi * bf_hi(v[i]);
        }
#pragma unroll
        for (int i = 0; i < 8; ++i) s[i] = t[i];
        e = ne;
        have = nhave;
    }
    for (; e < end; ++e) {
        const int ss = csr_src[e];
        const float wi = isd[ss] * si;
        const unsigned v = hh[(size_t)ss * 64 + lane];
        accx += wi * bf_lo(v);
        accy += wi * bf_hi(v);
    }
}

__global__ __launch_bounds__(256) void k_gather_fused2(const unsigned* __restrict__ hh,
                                                       const int* __restrict__ rowptr,
                                                       const int* __restrict__ csr_src,
                                                       const float* __restrict__ isd,
                                                       const float* __restrict__ Wc,
                                                       float* __restrict__ z) {
    __shared__ float2 part[2][64];
    const int tid = threadIdx.x;
    const int lane = tid & 63;
    const int waveid = tid >> 6;         // 0..3
    const int slot = waveid >> 1;        // node slot 0..1
    const int half = waveid & 1;         // 0 = primary, 1 = secondary
    const int node = (blockIdx.x << 1) + slot;   // < 50000 always (grid=25000)

    const float si = isd[node];
    const int e0 = rowptr[node], e1 = rowptr[node + 1];
    const int mid = e0 + ((e1 - e0) >> 1);

    float accx = 0.f, accy = 0.f;
    if (half == 0) {
        const unsigned a = hh[(size_t)node * 64 + lane];   // self-loop
        accx = bf_lo(a) * si * si;
        accy = bf_hi(a) * si * si;
        gather_range(hh, csr_src, isd, si, lane, e0, mid, accx, accy);
    } else {
        gather_range(hh, csr_src, isd, si, lane, mid, e1, accx, accy);
        part[slot][lane] = make_float2(accx, accy);
    }
    __syncthreads();
    if (half == 1) return;

    const float2 pb = part[slot][lane];
    accx += pb.x;
    accy += pb.y;

    // relu + Wc dot + wave reduction
    const float rx = fmaxf(accx, 0.f), ry = fmaxf(accy, 0.f);
    float p[16];
#pragma unroll
    for (int c = 0; c < 16; ++c) {
        const float2 wc = *(const float2*)(Wc + c * 128 + (lane << 1));
        p[c] = rx * wc.x + ry * wc.y;
    }
#pragma unroll
    for (int m = 1; m < 64; m <<= 1) {
#pragma unroll
        for (int c = 0; c < 16; ++c) p[c] += __shfl_xor(p[c], m, 64);
    }
    if (lane == 0) {
        float* zr = z + (size_t)node * 16;
        *(float4*)(zr + 0)  = make_float4(p[0],  p[1],  p[2],  p[3]);
        *(float4*)(zr + 4)  = make_float4(p[4],  p[5],  p[6],  p[7]);
        *(float4*)(zr + 8)  = make_float4(p[8],  p[9],  p[10], p[11]);
        *(float4*)(zr + 12) = make_float4(p[12], p[13], p[14], p[15]);
    }
}

// ---------------- gather (16-wide): 4 threads per node ----------------

__global__ __launch_bounds__(256) void k_gather16(const float4* __restrict__ z4,
                                                  const int* __restrict__ rowptr,
                                                  const int* __restrict__ csr_src,
                                                  const float* __restrict__ isd,
                                                  float4* __restrict__ out4) {
    int t = blockIdx.x * 256 + threadIdx.x;
    int n = t >> 2, q = t & 3;
    if (n >= N_NODES) return;
    const float si = isd[n];
    float4 a = z4[(size_t)n * 4 + q];
    float4 acc;
    acc.x = a.x * si * si; acc.y = a.y * si * si;
    acc.z = a.z * si * si; acc.w = a.w * si * si;
    int e = rowptr[n];
    const int end = rowptr[n + 1];
    for (; e + 4 <= end; e += 4) {
        int s0 = csr_src[e],     s1 = csr_src[e + 1];
        int s2 = csr_src[e + 2], s3 = csr_src[e + 3];
        float w0 = isd[s0] * si, w1 = isd[s1] * si;
        float w2 = isd[s2] * si, w3 = isd[s3] * si;
        float4 v0 = z4[(size_t)s0 * 4 + q];
        float4 v1 = z4[(size_t)s1 * 4 + q];
        float4 v2 = z4[(size_t)s2 * 4 + q];
        float4 v3 = z4[(size_t)s3 * 4 + q];
        acc.x += w0 * v0.x; acc.y += w0 * v0.y; acc.z += w0 * v0.z; acc.w += w0 * v0.w;
        acc.x += w1 * v1.x; acc.y += w1 * v1.y; acc.z += w1 * v1.z; acc.w += w1 * v1.w;
        acc.x += w2 * v2.x; acc.y += w2 * v2.y; acc.z += w2 * v2.z; acc.w += w2 * v2.w;
        acc.x += w3 * v3.x; acc.y += w3 * v3.y; acc.z += w3 * v3.z; acc.w += w3 * v3.w;
    }
    for (; e < end; ++e) {
        int s = csr_src[e];
        float w = isd[s] * si;
        float4 v = z4[(size_t)s * 4 + q];
        acc.x += w * v.x; acc.y += w * v.y; acc.z += w * v.z; acc.w += w * v.w;
    }
    out4[(size_t)n * 4 + q] = acc;
}

// ---------------- fallback (round-1 atomic path, all fp32) ----------------

__global__ void k_deg_init(float* __restrict__ deg) {
    int i = blockIdx.x * 256 + threadIdx.x;
    if (i < N_NODES) deg[i] = 1.0f;
}
__global__ void k_deg_count(const int* __restrict__ dst, float* __restrict__ deg, int E) {
    int e = blockIdx.x * 256 + threadIdx.x;
    if (e < E) atomicAdd(&deg[dst[e]], 1.0f);
}
__global__ void k_rsqrt(float* __restrict__ deg) {
    int i = blockIdx.x * 256 + threadIdx.x;
    if (i < N_NODES) deg[i] = rsqrtf(deg[i]);
}
__global__ void k_agg_init(const float4* __restrict__ h, const float* __restrict__ isd,
                           float4* __restrict__ agg) {
    int t = blockIdx.x * 256 + threadIdx.x;
    if (t < N_NODES * (F_HID / 4)) {
        int row = t >> 5;
        float s = isd[row];
        s = s * s;
        float4 v = h[t];
        v.x *= s; v.y *= s; v.z *= s; v.w *= s;
        agg[t] = v;
    }
}
__global__ void k_scatter(const float4* __restrict__ h, const int* __restrict__ src,
                          const int* __restrict__ dst, const float* __restrict__ isd,
                          float* __restrict__ agg, int E) {
    int t = blockIdx.x * 256 + threadIdx.x;
    int e = t >> 5, q = t & 31;
    if (e >= E) return;
    int s = src[e], d = dst[e];
    float norm = isd[s] * isd[d];
    float4 v = h[(long long)s * 32 + q];
    float* out = agg + (long long)d * F_HID + q * 4;
    atomicAdd(out + 0, v.x * norm);
    atomicAdd(out + 1, v.y * norm);
    atomicAdd(out + 2, v.z * norm);
    atomicAdd(out + 3, v.w * norm);
}
template <int BM, int BN, int BK, int TM, int TN, bool RELU_A>
__global__ __launch_bounds__(256) void gemm_nt(const float* __restrict__ A,
                                               const float* __restrict__ B,
                                               float* __restrict__ C,
                                               int M, int N, int K) {
    __shared__ float As[BK][BM + 1];
    __shared__ float Bs[BK][BN + 1];
    const int tid = threadIdx.x;
    const int NTX = BN / TN;
    const int tx = tid % NTX;
    const int ty = tid / NTX;
    const int m0 = blockIdx.x * BM;
    const int n0 = blockIdx.y * BN;
    float acc[TM][TN] = {};
    for (int k0 = 0; k0 < K; k0 += BK) {
        for (int idx = tid; idx < BM * BK; idx += 256) {
            int m = idx / BK, k = idx % BK;
            int gm = m0 + m;
            float v = (gm < M) ? A[(long long)gm * K + k0 + k] : 0.0f;
            if (RELU_A) v = fmaxf(v, 0.0f);
            As[k][m] = v;
        }
        for (int idx = tid; idx < BN * BK; idx += 256) {
            int n = idx / BK, k = idx % BK;
            int gn = n0 + n;
            Bs[k][n] = (gn < N) ? B[(long long)gn * K + k0 + k] : 0.0f;
        }
        __syncthreads();
        for (int k = 0; k < BK; ++k) {
            float a[TM], b[TN];
#pragma unroll
            for (int r = 0; r < TM; ++r) a[r] = As[k][ty * TM + r];
#pragma unroll
            for (int c = 0; c < TN; ++c) b[c] = Bs[k][c * NTX + tx];
#pragma unroll
            for (int r = 0; r < TM; ++r)
#pragma unroll
                for (int c = 0; c < TN; ++c) acc[r][c] += a[r] * b[c];
        }
        __syncthreads();
    }
#pragma unroll
    for (int r = 0; r < TM; ++r) {
        int gm = m0 + ty * TM + r;
        if (gm >= M) continue;
#pragma unroll
        for (int c = 0; c < TN; ++c) {
            int gn = n0 + c * NTX + tx;
            if (gn < N) C[(long long)gm * N + gn] = acc[r][c];
        }
    }
}
__global__ __launch_bounds__(256) void gemm_lin(const float* __restrict__ A,
                                                const float* __restrict__ W,
                                                float* __restrict__ C, int M) {
    __shared__ float Ws[16][129];
    __shared__ float As[16][129];
    const int tid = threadIdx.x;
    for (int idx = tid; idx < 16 * 128; idx += 256) Ws[idx >> 7][idx & 127] = W[idx];
    const int m0 = blockIdx.x * 16;
    for (int idx = tid; idx < 16 * 128; idx += 256) {
        int r = idx >> 7, k = idx & 127;
        int gm = m0 + r;
        As[r][k] = (gm < M) ? A[(long long)gm * 128 + k] : 0.0f;
    }
    __syncthreads();
    const int tc = tid & 15, tr = tid >> 4;
    float s = 0.f;
#pragma unroll 8
    for (int k = 0; k < 128; ++k) s += As[tr][k] * Ws[tc][k];
    int gm = m0 + tr;
    if (gm < M) C[gm * 16 + tc] = s;
}

// ---------------- launcher ----------------

static inline size_t align256(size_t x) { return (x + 255) & ~(size_t)255; }

extern "C" void kernel_launch(void* const* d_in, const int* in_sizes, int n_in,
                              void* d_out, int out_size, void* d_ws, size_t ws_size,
                              hipStream_t stream) {
    const float* x    = (const float*)d_in[0];
    const int*   ei   = (const int*)d_in[1];
    const float* W1   = (const float*)d_in[2];
    const float* W2   = (const float*)d_in[3];
    const float* Wlin = (const float*)d_in[4];
    float* out = (float*)d_out;

    const int E = in_sizes[1] / 2;
    const int* src = ei;
    const int* dst = ei + E;

    // workspace layout
    char* ws = (char*)d_ws;
    size_t off = 0;
    float* isd  = (float*)(ws + off); off += align256((size_t)N_NODES * 4);
    float* Wc   = (float*)(ws + off); off += align256(16 * 128 * 4);
    float* bufA = (float*)(ws + off); off += align256((size_t)N_NODES * F_HID * 4);
    float* bufB = (float*)(ws + off); off += align256((size_t)N_NODES * F_HID * 4);
    int*   hist    = (int*)(ws + off); off += align256((size_t)N_NODES * 4);
    int*   rowptr  = (int*)(ws + off); off += align256(((size_t)N_NODES + 1) * 4);
    int*   blksum  = (int*)(ws + off); off += align256(256 * 4);
    int*   csr_src = (int*)(ws + off); off += align256((size_t)E * 4);
    int*   rank    = (int*)(ws + off); off += align256((size_t)E * 4);
    ushort* wpk    = (ushort*)(ws + off); off += align256((size_t)16 * 8192 * 2);  // 256 KB
    const bool use_csr = (off <= ws_size);

    const int nblk_nodes = NSCAN_BLKS;
    const int nblk_edges = (E + 255) / 256;
    const int mtiles = (N_NODES + 63) / 64;

    if (use_csr) {
        unsigned* hb = (unsigned*)bufB;   // [N][64] packed bf16x2 (12.8 MB)
        float*    z  = bufA;              // [N][16] fp32

        // 1. CSR build + normalization (one atomic pass)
        hipMemsetAsync(hist, 0, (size_t)N_NODES * 4, stream);
        k_hist_rank<<<nblk_edges, 256, 0, stream>>>(dst, hist, rank, E);
        k_scan_local<<<nblk_nodes, 256, 0, stream>>>(hist, rowptr, blksum);
        k_scan_blk<<<1, 256, 0, stream>>>(blksum);
        k_finalize<<<nblk_nodes, 256, 0, stream>>>(hist, rowptr, blksum, isd, E);
        k_reorder<<<nblk_edges, 256, 0, stream>>>(src, dst, rank, rowptr, csr_src, E);
        // 2. Wc = Wlin @ W2 ; W1 fragment-major bf16 hi/lo pack (padded K=512)
        k_wc<<<16, 128, 0, stream>>>(W2, Wlin, Wc);
        k_w1pack<<<32, 256, 0, stream>>>(W1, wpk);
        // 3. h1 = x @ W1^T -> bf16 via MFMA (glds-staged B, dbuf, A prefetch)
        gemm1_mfma4<<<mtiles, 256, 0, stream>>>(x, wpk, hb, N_NODES);
        // 4+5. z = relu(A_norm * h1) @ Wc^T   (fused, 2 waves/node)
        k_gather_fused2<<<N_NODES / 2, 256, 0, stream>>>(
            hb, rowptr, csr_src, isd, Wc, z);
        // 6. out = A_norm * z
        k_gather16<<<(N_NODES * 4 + 255) / 256, 256, 0, stream>>>(
            (const float4*)z, rowptr, csr_src, isd, (float4*)out);
    } else {
        // fallback: atomic scatter path (fp32)
        const int nblk_feat = (N_NODES * (F_HID / 4) + 255) / 256;
        const int nblk_scatter = (int)(((long long)E * 32 + 255) / 256);
        k_deg_init<<<(N_NODES + 255) / 256, 256, 0, stream>>>(isd);
        k_deg_count<<<nblk_edges, 256, 0, stream>>>(dst, isd, E);
        k_rsqrt<<<(N_NODES + 255) / 256, 256, 0, stream>>>(isd);
        gemm_nt<64, 128, 20, 4, 8, false>
            <<<dim3(mtiles, 1), 256, 0, stream>>>(x, W1, bufA, N_NODES, F_HID, F_IN);
        k_agg_init<<<nblk_feat, 256, 0, stream>>>((const float4*)bufA, isd, (float4*)bufB);
        k_scatter<<<nblk_scatter, 256, 0, stream>>>((const float4*)bufA, src, dst, isd, bufB, E);
        gemm_nt<64, 128, 16, 4, 8, true>
            <<<dim3(mtiles, 1), 256, 0, stream>>>(bufB, W2, bufA, N_NODES, F_HID, F_HID);
        k_agg_init<<<nblk_feat, 256, 0, stream>>>((const float4*)bufA, isd, (float4*)bufB);
        k_scatter<<<nblk_scatter, 256, 0, stream>>>((const float4*)bufA, src, dst, isd, bufB, E);
        gemm_lin<<<(N_NODES + 15) / 16, 256, 0, stream>>>(bufB, Wlin, out, N_NODES);
    }
}

// Round 5
// 405.064 us; speedup vs baseline: 1.2793x; 1.0788x over previous
//
#include <hip/hip_runtime.h>

#define N_NODES 50000
#define F_IN 500
#define F_HID 128
#define F_OUT 16
#define NSCAN_BLKS ((N_NODES + 255) / 256)   // 196

// ---------------- bf16 helpers (RTNE pack, shift decode) ----------------

__device__ __forceinline__ unsigned bf16_pack2(float a, float b) {
    unsigned ua = __float_as_uint(a);
    unsigned ub = __float_as_uint(b);
    ua = (ua + 0x7fffu + ((ua >> 16) & 1u)) >> 16;
    ub = (ub + 0x7fffu + ((ub >> 16) & 1u)) >> 16;
    return ua | (ub << 16);
}
__device__ __forceinline__ float bf_lo(unsigned v) { return __uint_as_float(v << 16); }
__device__ __forceinline__ float bf_hi(unsigned v) { return __uint_as_float(v & 0xffff0000u); }

__device__ __forceinline__ unsigned bf16_rtne(float a) {
    unsigned u = __float_as_uint(a);
    return (u + 0x7fffu + ((u >> 16) & 1u)) >> 16;
}

// ---------------- CSR build (single atomic pass, round-9 proven) ----------------

__global__ void k_hist_rank(const int* __restrict__ dst, int* __restrict__ hist,
                            int* __restrict__ rank, int E) {
    int e = blockIdx.x * 256 + threadIdx.x;
    if (e < E) rank[e] = atomicAdd(&hist[dst[e]], 1);
}

__global__ __launch_bounds__(256) void k_scan_local(const int* __restrict__ hist,
                                                    int* __restrict__ rowptr,
                                                    int* __restrict__ blksum) {
    __shared__ int s[256];
    const int tid = threadIdx.x;
    const int i = blockIdx.x * 256 + tid;
    int v = (i < N_NODES) ? hist[i] : 0;
    s[tid] = v;
    __syncthreads();
#pragma unroll
    for (int ofs = 1; ofs < 256; ofs <<= 1) {
        int t = (tid >= ofs) ? s[tid - ofs] : 0;
        __syncthreads();
        if (tid >= ofs) s[tid] += t;
        __syncthreads();
    }
    if (i < N_NODES) rowptr[i] = s[tid] - v;
    if (tid == 255) blksum[blockIdx.x] = s[255];
}

__global__ __launch_bounds__(256) void k_scan_blk(int* __restrict__ blksum) {
    __shared__ int s[256];
    const int tid = threadIdx.x;
    int v = (tid < NSCAN_BLKS) ? blksum[tid] : 0;
    s[tid] = v;
    __syncthreads();
#pragma unroll
    for (int ofs = 1; ofs < 256; ofs <<= 1) {
        int t = (tid >= ofs) ? s[tid - ofs] : 0;
        __syncthreads();
        if (tid >= ofs) s[tid] += t;
        __syncthreads();
    }
    if (tid < NSCAN_BLKS) blksum[tid] = s[tid] - v;
}

__global__ void k_finalize(const int* __restrict__ hist, int* __restrict__ rowptr,
                           const int* __restrict__ blksum, float* __restrict__ isd, int E) {
    int i = blockIdx.x * 256 + threadIdx.x;
    if (i < N_NODES) {
        rowptr[i] = rowptr[i] + blksum[i >> 8];
        isd[i] = rsqrtf((float)(hist[i] + 1));  // +1 self-loop
    }
    if (i == 0) rowptr[N_NODES] = E;
}

__global__ void k_reorder(const int* __restrict__ src, const int* __restrict__ dst,
                          const int* __restrict__ rank, const int* __restrict__ rowptr,
                          int* __restrict__ csr_src, int E) {
    int e = blockIdx.x * 256 + threadIdx.x;
    if (e >= E) return;
    csr_src[rowptr[dst[e]] + rank[e]] = src[e];
}

// ---------------- Wc = Wlin @ W2  [16,128] ----------------

__global__ void k_wc(const float* __restrict__ W2, const float* __restrict__ Wlin,
                     float* __restrict__ Wc) {
    const int c = blockIdx.x;       // 0..15
    const int j = threadIdx.x;      // 0..127
    const float* wl = Wlin + c * 128;
    float acc = 0.f;
#pragma unroll 4
    for (int k = 0; k < 128; ++k) acc += wl[k] * W2[k * 128 + j];
    Wc[c * 128 + j] = acc;
}

// ---------------- W1 pack: fragment-major bf16 hi/lo, padded K 500->512 ----------------
// Layout: wpk[kt][f][h][lane][8]  (ushort), h=0 hi, h=1 lo.
// For (kt,f,lane,j): n = 16f + (lane&15), k = kt*32 + (lane>>4)*8 + j.
// A wave's B-fragment load for (kt,f,h) is then 64 lanes x 16 B fully contiguous,
// and the glds staging order (lane l -> base + l*16B) matches it exactly.

__global__ __launch_bounds__(256) void k_w1pack(const float* __restrict__ W1,
                                                ushort* __restrict__ wpk) {
    int t = blockIdx.x * 256 + threadIdx.x;   // (kt*8+f)*64 + lane ; 8192 total
    if (t >= 8192) return;
    const int lane = t & 63;
    const int fkt = t >> 6;
    const int f = fkt & 7;
    const int kt = fkt >> 3;
    const int n = (f << 4) + (lane & 15);
    const int kb = (kt << 5) + ((lane >> 4) << 3);
    ushort h8[8], l8[8];
#pragma unroll
    for (int j = 0; j < 8; ++j) {
        const int k = kb + j;
        float v = (k < F_IN) ? W1[n * F_IN + k] : 0.f;
        unsigned h = bf16_rtne(v);
        float fh = __uint_as_float(h << 16);
        unsigned l = bf16_rtne(v - fh);      // Dekker residual, exact in fp32
        h8[j] = (ushort)h;
        l8[j] = (ushort)l;
    }
    const size_t base = ((size_t)fkt << 10);         // (kt*8+f)*1024 elements
    *(uint4*)(wpk + base + (lane << 3))       = *(const uint4*)h8;
    *(uint4*)(wpk + base + 512 + (lane << 3)) = *(const uint4*)l8;
}

// ---------------- GEMM1 via MFMA + glds-staged B: g[M,128](bf16) = isd * (A @ W1^T) ----
// 3-pass Dekker split (Ahi*Whi + Alo*Whi + Ahi*Wlo) = fp32-equivalent accuracy.
// Epilogue scales row m by isd[m] BEFORE the bf16 pack (same single rounding as
// before — bf16(isd*h) replaces bf16(h)), so the edge gathers need no weights:
// out1[i] = isd_i * (sum_{j->i} g_j + g_i).
// B tile staged via global_load_lds w=16 (zero staging VGPRs; round-3 reg-staging
// spilled: WRITE_SIZE 12.5->158 MB). Double-buffered, one barrier/kt.

typedef __attribute__((ext_vector_type(8))) short s16x8;
typedef __attribute__((ext_vector_type(4))) float f32x4;

typedef const __attribute__((address_space(1))) unsigned u32_glb;
typedef __attribute__((address_space(3))) unsigned u32_lds;

__device__ __forceinline__ void glds16(const void* g, void* l) {
    __builtin_amdgcn_global_load_lds((u32_glb*)g, (u32_lds*)l, 16, 0, 0);
}

__global__ __launch_bounds__(256) void gemm1_mfma5(const float* __restrict__ A,
                                                   const ushort* __restrict__ wpk,
                                                   const float* __restrict__ isd,
                                                   unsigned* __restrict__ hb, int M) {
    __shared__ __align__(16) ushort Bs[2][8192];   // 2 x 16 KB

    const int tid = threadIdx.x;
    const int lane = tid & 63;
    const int wave = tid >> 6;                // 0..3
    const int jcol = lane & 15;
    const int kgrp = lane >> 4;
    const int klo  = kgrp << 3;

    const int m0  = blockIdx.x * 64 + wave * 16;
    const int arw = m0 + jcol;
    const float* arow = A + (size_t)((arw < M) ? arw : (M - 1)) * F_IN;

    // wave-uniform LDS dest + per-lane contiguous global src (glds: dst + lane*16)
#define ISSUE_TILE(KT, B)                                                        \
    {                                                                            \
        const ushort* tb_ = wpk + ((size_t)(KT) << 13);                          \
        _Pragma("unroll") for (int c_ = 0; c_ < 4; ++c_) {                       \
            glds16(tb_ + ((c_ * 256 + wave * 64 + lane) << 3),                   \
                   &Bs[B][(c_ * 256 + wave * 64) << 3]);                         \
        }                                                                        \
    }

    const float4 zf4 = make_float4(0.f, 0.f, 0.f, 0.f);
    float4 ca0 = zf4, ca1 = zf4;

    // ---- prologue: issue tile 0, load A(0) ----
    ISSUE_TILE(0, 0);
    ca0 = *(const float4*)(arow + klo);        // kt=0: klo+8 <= 32 < 500
    ca1 = *(const float4*)(arow + klo + 4);
    __syncthreads();   // barrier drains vmcnt -> tile 0 visible

    f32x4 acc[8] = {};

    for (int kt = 0; kt < 16; ++kt) {
        const int cb = kt & 1, nb = (kt + 1) & 1;

        // ---- issue next B tile (async, overlaps this kt's compute) + prefetch next A ----
        float4 na0 = zf4, na1 = zf4;
        if (kt + 1 < 16) {
            ISSUE_TILE(kt + 1, nb);
            const int k = ((kt + 1) << 5) + klo;
            if (k + 8 <= F_IN) {
                na0 = *(const float4*)(arow + k);
                na1 = *(const float4*)(arow + k + 4);
            } else {
                float tmp[8];
#pragma unroll
                for (int i = 0; i < 8; ++i) tmp[i] = (k + i < F_IN) ? arow[k + i] : 0.f;
                na0 = make_float4(tmp[0], tmp[1], tmp[2], tmp[3]);
                na1 = make_float4(tmp[4], tmp[5], tmp[6], tmp[7]);
            }
        }

        // ---- Dekker split current A ----
        const float av[8] = {ca0.x, ca0.y, ca0.z, ca0.w, ca1.x, ca1.y, ca1.z, ca1.w};
        s16x8 ahi, alo;
#pragma unroll
        for (int i = 0; i < 8; ++i) {
            unsigned h = bf16_rtne(av[i]);
            float fh = __uint_as_float(h << 16);
            unsigned l = bf16_rtne(av[i] - fh);
            ahi[i] = (short)h;
            alo[i] = (short)l;
        }

        // ---- 8 column fragments from LDS x 3 MFMA passes ----
#pragma unroll
        for (int f = 0; f < 8; ++f) {
            const s16x8 bh = *(const s16x8*)&Bs[cb][(f << 10) + (lane << 3)];
            const s16x8 bl = *(const s16x8*)&Bs[cb][(f << 10) + 512 + (lane << 3)];
            acc[f] = __builtin_amdgcn_mfma_f32_16x16x32_bf16(ahi, bh, acc[f], 0, 0, 0);
            acc[f] = __builtin_amdgcn_mfma_f32_16x16x32_bf16(alo, bh, acc[f], 0, 0, 0);
            acc[f] = __builtin_amdgcn_mfma_f32_16x16x32_bf16(ahi, bl, acc[f], 0, 0, 0);
        }

        ca0 = na0;
        ca1 = na1;
        __syncthreads();   // tile kt+1 staged; buffer cb free for next issue
    }
#undef ISSUE_TILE

    // ---- epilogue: scale by isd[row], pack adjacent features via shfl ----
    const int orow = m0 + (kgrp << 2);
    float sr[4];
#pragma unroll
    for (int r = 0; r < 4; ++r) {
        const int m = orow + r;
        sr[r] = (m < M) ? isd[m] : 0.f;
    }
#pragma unroll
    for (int f = 0; f < 8; ++f) {
#pragma unroll
        for (int r = 0; r < 4; ++r) {
            float v = acc[f][r] * sr[r];
            float o = __shfl_xor(v, 1, 64);
            if (!(jcol & 1)) {
                const int m = orow + r;
                if (m < M)
                    hb[(size_t)m * 64 + (f << 3) + (jcol >> 1)] = bf16_pack2(v, o);
            }
        }
    }
}

// ---------------- fused gather + zlin, TWO waves per node ----------------
// g rows are pre-scaled by isd (see gemm1_mfma5) -> edge loop is PURE summation:
// no per-edge isd load (round-4's unhidden-latency stall), no per-edge mul.

__device__ __forceinline__ void gather_range(const unsigned* __restrict__ hh,
                                             const int* __restrict__ csr_src,
                                             int lane, int e, int end,
                                             float& accx, float& accy) {
    int s[8], t[8];
    bool have = (e + 8 <= end);
    if (have) {
#pragma unroll
        for (int i = 0; i < 8; ++i) s[i] = csr_src[e + i];
    }
    while (have) {
        unsigned v[8];
#pragma unroll
        for (int i = 0; i < 8; ++i) v[i] = hh[(size_t)s[i] * 64 + lane];
        const int ne = e + 8;
        const bool nhave = (ne + 8 <= end);
        if (nhave) {
#pragma unroll
            for (int i = 0; i < 8; ++i) t[i] = csr_src[ne + i];
        }
#pragma unroll
        for (int i = 0; i < 8; ++i) {
            accx += bf_lo(v[i]);
            accy += bf_hi(v[i]);
        }
#pragma unroll
        for (int i = 0; i < 8; ++i) s[i] = t[i];
        e = ne;
        have = nhave;
    }
    // masked tail batch (<8): all loads independent, compile-time indexing only
    if (e < end) {
        const int last = end - 1;
        int ss[8];
        unsigned vv[8];
#pragma unroll
        for (int i = 0; i < 8; ++i) ss[i] = csr_src[(e + i < end) ? e + i : last];
#pragma unroll
        for (int i = 0; i < 8; ++i) vv[i] = hh[(size_t)ss[i] * 64 + lane];
#pragma unroll
        for (int i = 0; i < 8; ++i) {
            if (e + i < end) {
                accx += bf_lo(vv[i]);
                accy += bf_hi(vv[i]);
            }
        }
    }
}

__global__ __launch_bounds__(256) void k_gather_fused2(const unsigned* __restrict__ hh,
                                                       const int* __restrict__ rowptr,
                                                       const int* __restrict__ csr_src,
                                                       const float* __restrict__ isd,
                                                       const float* __restrict__ Wc,
                                                       float* __restrict__ z) {
    __shared__ float2 part[2][64];
    const int tid = threadIdx.x;
    const int lane = tid & 63;
    const int waveid = tid >> 6;         // 0..3
    const int slot = waveid >> 1;        // node slot 0..1
    const int half = waveid & 1;         // 0 = primary, 1 = secondary
    const int node = (blockIdx.x << 1) + slot;   // < 50000 always (grid=25000)

    const int e0 = rowptr[node], e1 = rowptr[node + 1];
    const int mid = e0 + ((e1 - e0) >> 1);

    float accx = 0.f, accy = 0.f;
    if (half == 0) {
        const unsigned a = hh[(size_t)node * 64 + lane];   // self-loop: g_i
        accx = bf_lo(a);
        accy = bf_hi(a);
        gather_range(hh, csr_src, lane, e0, mid, accx, accy);
    } else {
        gather_range(hh, csr_src, lane, mid, e1, accx, accy);
        part[slot][lane] = make_float2(accx, accy);
    }
    __syncthreads();
    if (half == 1) return;

    const float2 pb = part[slot][lane];
    accx += pb.x;
    accy += pb.y;

    // layer-1 output = relu(si * acc); project; store zg = si * (proj) for layer 2
    const float si = isd[node];
    const float rx = fmaxf(accx * si, 0.f), ry = fmaxf(accy * si, 0.f);
    float p[16];
#pragma unroll
    for (int c = 0; c < 16; ++c) {
        const float2 wc = *(const float2*)(Wc + c * 128 + (lane << 1));
        p[c] = rx * wc.x + ry * wc.y;
    }
#pragma unroll
    for (int m = 1; m < 64; m <<= 1) {
#pragma unroll
        for (int c = 0; c < 16; ++c) p[c] += __shfl_xor(p[c], m, 64);
    }
    if (lane == 0) {
        float* zr = z + (size_t)node * 16;
        *(float4*)(zr + 0)  = make_float4(si * p[0],  si * p[1],  si * p[2],  si * p[3]);
        *(float4*)(zr + 4)  = make_float4(si * p[4],  si * p[5],  si * p[6],  si * p[7]);
        *(float4*)(zr + 8)  = make_float4(si * p[8],  si * p[9],  si * p[10], si * p[11]);
        *(float4*)(zr + 12) = make_float4(si * p[12], si * p[13], si * p[14], si * p[15]);
    }
}

// ---------------- gather (16-wide): 4 threads per node ----------------
// z rows are pre-scaled (zg = isd*z) -> pure summation + one final si scale.

__global__ __launch_bounds__(256) void k_gather16(const float4* __restrict__ z4,
                                                  const int* __restrict__ rowptr,
                                                  const int* __restrict__ csr_src,
                                                  const float* __restrict__ isd,
                                                  float4* __restrict__ out4) {
    int t = blockIdx.x * 256 + threadIdx.x;
    int n = t >> 2, q = t & 3;
    if (n >= N_NODES) return;
    const float si = isd[n];
    float4 acc = z4[(size_t)n * 4 + q];      // self-loop: zg_i
    int e = rowptr[n];
    const int end = rowptr[n + 1];
    for (; e + 4 <= end; e += 4) {
        int s0 = csr_src[e],     s1 = csr_src[e + 1];
        int s2 = csr_src[e + 2], s3 = csr_src[e + 3];
        float4 v0 = z4[(size_t)s0 * 4 + q];
        float4 v1 = z4[(size_t)s1 * 4 + q];
        float4 v2 = z4[(size_t)s2 * 4 + q];
        float4 v3 = z4[(size_t)s3 * 4 + q];
        acc.x += v0.x + v1.x + v2.x + v3.x;
        acc.y += v0.y + v1.y + v2.y + v3.y;
        acc.z += v0.z + v1.z + v2.z + v3.z;
        acc.w += v0.w + v1.w + v2.w + v3.w;
    }
    for (; e < end; ++e) {
        int s = csr_src[e];
        float4 v = z4[(size_t)s * 4 + q];
        acc.x += v.x; acc.y += v.y; acc.z += v.z; acc.w += v.w;
    }
    acc.x *= si; acc.y *= si; acc.z *= si; acc.w *= si;
    out4[(size_t)n * 4 + q] = acc;
}

// ---------------- fallback (round-1 atomic path, all fp32) ----------------

__global__ void k_deg_init(float* __restrict__ deg) {
    int i = blockIdx.x * 256 + threadIdx.x;
    if (i < N_NODES) deg[i] = 1.0f;
}
__global__ void k_deg_count(const int* __restrict__ dst, float* __restrict__ deg, int E) {
    int e = blockIdx.x * 256 + threadIdx.x;
    if (e < E) atomicAdd(&deg[dst[e]], 1.0f);
}
__global__ void k_rsqrt(float* __restrict__ deg) {
    int i = blockIdx.x * 256 + threadIdx.x;
    if (i < N_NODES) deg[i] = rsqrtf(deg[i]);
}
__global__ void k_agg_init(const float4* __restrict__ h, const float* __restrict__ isd,
                           float4* __restrict__ agg) {
    int t = blockIdx.x * 256 + threadIdx.x;
    if (t < N_NODES * (F_HID / 4)) {
        int row = t >> 5;
        float s = isd[row];
        s = s * s;
        float4 v = h[t];
        v.x *= s; v.y *= s; v.z *= s; v.w *= s;
        agg[t] = v;
    }
}
__global__ void k_scatter(const float4* __restrict__ h, const int* __restrict__ src,
                          const int* __restrict__ dst, const float* __restrict__ isd,
                          float* __restrict__ agg, int E) {
    int t = blockIdx.x * 256 + threadIdx.x;
    int e = t >> 5, q = t & 31;
    if (e >= E) return;
    int s = src[e], d = dst[e];
    float norm = isd[s] * isd[d];
    float4 v = h[(long long)s * 32 + q];
    float* out = agg + (long long)d * F_HID + q * 4;
    atomicAdd(out + 0, v.x * norm);
    atomicAdd(out + 1, v.y * norm);
    atomicAdd(out + 2, v.z * norm);
    atomicAdd(out + 3, v.w * norm);
}
template <int BM, int BN, int BK, int TM, int TN, bool RELU_A>
__global__ __launch_bounds__(256) void gemm_nt(const float* __restrict__ A,
                                               const float* __restrict__ B,
                                               float* __restrict__ C,
                                               int M, int N, int K) {
    __shared__ float As[BK][BM + 1];
    __shared__ float Bs[BK][BN + 1];
    const int tid = threadIdx.x;
    const int NTX = BN / TN;
    const int tx = tid % NTX;
    const int ty = tid / NTX;
    const int m0 = blockIdx.x * BM;
    const int n0 = blockIdx.y * BN;
    float acc[TM][TN] = {};
    for (int k0 = 0; k0 < K; k0 += BK) {
        for (int idx = tid; idx < BM * BK; idx += 256) {
            int m = idx / BK, k = idx % BK;
            int gm = m0 + m;
            float v = (gm < M) ? A[(long long)gm * K + k0 + k] : 0.0f;
            if (RELU_A) v = fmaxf(v, 0.0f);
            As[k][m] = v;
        }
        for (int idx = tid; idx < BN * BK; idx += 256) {
            int n = idx / BK, k = idx % BK;
            int gn = n0 + n;
            Bs[k][n] = (gn < N) ? B[(long long)gn * K + k0 + k] : 0.0f;
        }
        __syncthreads();
        for (int k = 0; k < BK; ++k) {
            float a[TM], b[TN];
#pragma unroll
            for (int r = 0; r < TM; ++r) a[r] = As[k][ty * TM + r];
#pragma unroll
            for (int c = 0; c < TN; ++c) b[c] = Bs[k][c * NTX + tx];
#pragma unroll
            for (int r = 0; r < TM; ++r)
#pragma unroll
                for (int c = 0; c < TN; ++c) acc[r][c] += a[r] * b[c];
        }
        __syncthreads();
    }
#pragma unroll
    for (int r = 0; r < TM; ++r) {
        int gm = m0 + ty * TM + r;
        if (gm >= M) continue;
#pragma unroll
        for (int c = 0; c < TN; ++c) {
            int gn = n0 + c * NTX + tx;
            if (gn < N) C[(long long)gm * N + gn] = acc[r][c];
        }
    }
}
__global__ __launch_bounds__(256) void gemm_lin(const float* __restrict__ A,
                                                const float* __restrict__ W,
                                                float* __restrict__ C, int M) {
    __shared__ float Ws[16][129];
    __shared__ float As[16][129];
    const int tid = threadIdx.x;
    for (int idx = tid; idx < 16 * 128; idx += 256) Ws[idx >> 7][idx & 127] = W[idx];
    const int m0 = blockIdx.x * 16;
    for (int idx = tid; idx < 16 * 128; idx += 256) {
        int r = idx >> 7, k = idx & 127;
        int gm = m0 + r;
        As[r][k] = (gm < M) ? A[(long long)gm * 128 + k] : 0.0f;
    }
    __syncthreads();
    const int tc = tid & 15, tr = tid >> 4;
    float s = 0.f;
#pragma unroll 8
    for (int k = 0; k < 128; ++k) s += As[tr][k] * Ws[tc][k];
    int gm = m0 + tr;
    if (gm < M) C[gm * 16 + tc] = s;
}

// ---------------- launcher ----------------

static inline size_t align256(size_t x) { return (x + 255) & ~(size_t)255; }

extern "C" void kernel_launch(void* const* d_in, const int* in_sizes, int n_in,
                              void* d_out, int out_size, void* d_ws, size_t ws_size,
                              hipStream_t stream) {
    const float* x    = (const float*)d_in[0];
    const int*   ei   = (const int*)d_in[1];
    const float* W1   = (const float*)d_in[2];
    const float* W2   = (const float*)d_in[3];
    const float* Wlin = (const float*)d_in[4];
    float* out = (float*)d_out;

    const int E = in_sizes[1] / 2;
    const int* src = ei;
    const int* dst = ei + E;

    // workspace layout
    char* ws = (char*)d_ws;
    size_t off = 0;
    float* isd  = (float*)(ws + off); off += align256((size_t)N_NODES * 4);
    float* Wc   = (float*)(ws + off); off += align256(16 * 128 * 4);
    float* bufA = (float*)(ws + off); off += align256((size_t)N_NODES * F_HID * 4);
    float* bufB = (float*)(ws + off); off += align256((size_t)N_NODES * F_HID * 4);
    int*   hist    = (int*)(ws + off); off += align256((size_t)N_NODES * 4);
    int*   rowptr  = (int*)(ws + off); off += align256(((size_t)N_NODES + 1) * 4);
    int*   blksum  = (int*)(ws + off); off += align256(256 * 4);
    int*   csr_src = (int*)(ws + off); off += align256((size_t)E * 4);
    int*   rank    = (int*)(ws + off); off += align256((size_t)E * 4);
    ushort* wpk    = (ushort*)(ws + off); off += align256((size_t)16 * 8192 * 2);  // 256 KB
    const bool use_csr = (off <= ws_size);

    const int nblk_nodes = NSCAN_BLKS;
    const int nblk_edges = (E + 255) / 256;
    const int mtiles = (N_NODES + 63) / 64;

    if (use_csr) {
        unsigned* hb = (unsigned*)bufB;   // [N][64] packed bf16x2, pre-scaled by isd
        float*    z  = bufA;              // [N][16] fp32, pre-scaled by isd

        // 1. CSR build + normalization (one atomic pass)
        hipMemsetAsync(hist, 0, (size_t)N_NODES * 4, stream);
        k_hist_rank<<<nblk_edges, 256, 0, stream>>>(dst, hist, rank, E);
        k_scan_local<<<nblk_nodes, 256, 0, stream>>>(hist, rowptr, blksum);
        k_scan_blk<<<1, 256, 0, stream>>>(blksum);
        k_finalize<<<nblk_nodes, 256, 0, stream>>>(hist, rowptr, blksum, isd, E);
        k_reorder<<<nblk_edges, 256, 0, stream>>>(src, dst, rank, rowptr, csr_src, E);
        // 2. Wc = Wlin @ W2 ; W1 fragment-major bf16 hi/lo pack (padded K=512)
        k_wc<<<16, 128, 0, stream>>>(W2, Wlin, Wc);
        k_w1pack<<<32, 256, 0, stream>>>(W1, wpk);
        // 3. g = isd * (x @ W1^T) -> bf16 via MFMA (glds-staged B, dbuf, A prefetch)
        gemm1_mfma5<<<mtiles, 256, 0, stream>>>(x, wpk, isd, hb, N_NODES);
        // 4+5. zg = isd * ( relu(isd * (sum g)) @ Wc^T )   (fused, 2 waves/node)
        k_gather_fused2<<<N_NODES / 2, 256, 0, stream>>>(
            hb, rowptr, csr_src, isd, Wc, z);
        // 6. out = isd * (sum zg)
        k_gather16<<<(N_NODES * 4 + 255) / 256, 256, 0, stream>>>(
            (const float4*)z, rowptr, csr_src, isd, (float4*)out);
    } else {
        // fallback: atomic scatter path (fp32)
        const int nblk_feat = (N_NODES * (F_HID / 4) + 255) / 256;
        const int nblk_scatter = (int)(((long long)E * 32 + 255) / 256);
        k_deg_init<<<(N_NODES + 255) / 256, 256, 0, stream>>>(isd);
        k_deg_count<<<nblk_edges, 256, 0, stream>>>(dst, isd, E);
        k_rsqrt<<<(N_NODES + 255) / 256, 256, 0, stream>>>(isd);
        gemm_nt<64, 128, 20, 4, 8, false>
            <<<dim3(mtiles, 1), 256, 0, stream>>>(x, W1, bufA, N_NODES, F_HID, F_IN);
        k_agg_init<<<nblk_feat, 256, 0, stream>>>((const float4*)bufA, isd, (float4*)bufB);
        k_scatter<<<nblk_scatter, 256, 0, stream>>>((const float4*)bufA, src, dst, isd, bufB, E);
        gemm_nt<64, 128, 16, 4, 8, true>
            <<<dim3(mtiles, 1), 256, 0, stream>>>(bufB, W2, bufA, N_NODES, F_HID, F_HID);
        k_agg_init<<<nblk_feat, 256, 0, stream>>>((const float4*)bufA, isd, (float4*)bufB);
        k_scatter<<<nblk_scatter, 256, 0, stream>>>((const float4*)bufA, src, dst, isd, bufB, E);
        gemm_lin<<<(N_NODES + 15) / 16, 256, 0, stream>>>(bufB, Wlin, out, N_NODES);
    }
}